// Round 1
// baseline (2598.787 us; speedup 1.0000x reference)
//
#include <hip/hip_runtime.h>
#include <hip/hip_bf16.h>
#include <stdint.h>

typedef __attribute__((ext_vector_type(8))) short s16x8;
typedef __attribute__((ext_vector_type(4))) short s16x4;
typedef __attribute__((ext_vector_type(4))) float f32x4;

#define L_T 12
#define P_S 4
#define NMAT 16
#define MROWS 6304
#define PD 128
#define DT 768
#define DS 384
#define KSUB 16
#define KS_COV 8
#define NIT 48

// ---- workspace byte offsets (all 16B aligned) ----
// zt  : 16*128*6304 f32 = 51,642,368 B  (z stored TRANSPOSED: [mat][q][m])
// sp  : 16*8*16384 f32   = 8,388,608 B
// mu  : 2048 f32
// covb: 16*16384 bf16
// U   : 16*16*128 f32
// cross 144, gram 48, w 48 f32
#define ZT_B    0
#define SP_B    51642368
#define MU_B    60030976
#define COV_B   60039168
#define U_B     60563456
#define CROSS_B 60694528
#define GRAM_B  60695104
#define W_B     60695296

__device__ __forceinline__ short f2bf(float f) {
    __hip_bfloat16 h = __float2bfloat16(f);
    return *reinterpret_cast<short*>(&h);
}

// ------------------------------------------------------------------
// K1: z = tokens @ phi^T, written transposed: zt[mat][q][m]  (fp32)
// grid (50, nmat), block 256. BM=128, BN=128(all q), BK=32.
// ------------------------------------------------------------------
__global__ __launch_bounds__(256) void k_zgemm(const float* __restrict__ A,
                                               const float* __restrict__ W,
                                               float* __restrict__ zt,
                                               int D, int matBase) {
    __shared__ float As[128][36];
    __shared__ float Ws[128][36];
    int mat = matBase + blockIdx.y;
    const float* Ab = A + (size_t)blockIdx.y * MROWS * D;
    int m0 = blockIdx.x * 128;
    int tid = threadIdx.x;
    int tq = tid & 15, tm = tid >> 4;   // interleaved-16 tiles (bank-conflict free)
    float acc[8][8];
#pragma unroll
    for (int i = 0; i < 8; i++)
#pragma unroll
        for (int j = 0; j < 8; j++) acc[i][j] = 0.f;

    for (int d0 = 0; d0 < D; d0 += 32) {
        __syncthreads();
#pragma unroll
        for (int ii = 0; ii < 4; ii++) {
            int f = tid + 256 * ii;            // 0..1023
            int row = f >> 3, c4 = (f & 7) << 2;
            int m = m0 + row;
            float4 v = make_float4(0.f, 0.f, 0.f, 0.f);
            if (m < MROWS) v = *(const float4*)(Ab + (size_t)m * D + d0 + c4);
            *(float4*)&As[row][c4] = v;
            float4 wv = *(const float4*)(W + (size_t)row * D + d0 + c4);
            *(float4*)&Ws[row][c4] = wv;
        }
        __syncthreads();
#pragma unroll
        for (int k4 = 0; k4 < 32; k4 += 4) {
            float4 a4[8], b4[8];
#pragma unroll
            for (int i = 0; i < 8; i++) a4[i] = *(float4*)&As[tm + 16 * i][k4];
#pragma unroll
            for (int j = 0; j < 8; j++) b4[j] = *(float4*)&Ws[tq + 16 * j][k4];
#pragma unroll
            for (int i = 0; i < 8; i++)
#pragma unroll
                for (int j = 0; j < 8; j++) {
                    acc[i][j] += a4[i].x * b4[j].x + a4[i].y * b4[j].y +
                                 a4[i].z * b4[j].z + a4[i].w * b4[j].w;
                }
        }
    }
    float* zb = zt + (size_t)mat * PD * MROWS;
#pragma unroll
    for (int j = 0; j < 8; j++) {
        int q = tq + 16 * j;
#pragma unroll
        for (int i = 0; i < 8; i++) {
            int m = m0 + tm + 16 * i;
            if (m < MROWS) zb[(size_t)q * MROWS + m] = acc[i][j];
        }
    }
}

// ------------------------------------------------------------------
// K2: column means mu[mat][q]. grid 16, block 1024.
// ------------------------------------------------------------------
__global__ __launch_bounds__(1024) void k_means(const float* __restrict__ zt,
                                                float* __restrict__ mu) {
    __shared__ float red[128][8];
    int mat = blockIdx.x;
    int tid = threadIdx.x;
    int q = tid >> 3, sub = tid & 7;
    const float* zr = zt + (size_t)(mat * PD + q) * MROWS;
    float s = 0.f;
    for (int f = sub; f < MROWS / 4; f += 8) {
        float4 v = *(const float4*)(zr + 4 * f);
        s += v.x + v.y + v.z + v.w;
    }
    red[q][sub] = s;
    __syncthreads();
    if (tid < 128) {
        float t = 0.f;
#pragma unroll
        for (int k = 0; k < 8; k++) t += red[tid][k];
        mu[mat * PD + tid] = t * (1.0f / MROWS);
    }
}

// ------------------------------------------------------------------
// K3: S-partials via bf16 MFMA. grid (KS_COV,16), block 256.
// S[i][j] = sum_m z[m][i]z[m][j]; z transposed so rows are m-contiguous.
// ------------------------------------------------------------------
__global__ __launch_bounds__(256) void k_covp(const float* __restrict__ zt,
                                              float* __restrict__ spart) {
    __shared__ short Zb[128][40];   // bf16 bits, 32 m + 8 pad
    int mat = blockIdx.y, ks = blockIdx.x;
    int c0 = (ks * 197) / KS_COV, c1 = ((ks + 1) * 197) / KS_COV;
    int tid = threadIdx.x;
    int wid = tid >> 6, lane = tid & 63;
    int rw = lane & 15, kb = lane >> 4;
    f32x4 acc[2][8];
#pragma unroll
    for (int r = 0; r < 2; r++)
#pragma unroll
        for (int cc = 0; cc < 8; cc++) acc[r][cc] = (f32x4){0.f, 0.f, 0.f, 0.f};

    const float* zb = zt + (size_t)mat * PD * MROWS;
    for (int c = c0; c < c1; c++) {
        int m0 = c * 32;
        __syncthreads();
        {
            int q = tid >> 1, mh = (tid & 1) << 4;
            const float* src = zb + (size_t)q * MROWS + m0 + mh;
            float4 va = *(const float4*)(src);
            float4 vb = *(const float4*)(src + 4);
            float4 vc = *(const float4*)(src + 8);
            float4 vd = *(const float4*)(src + 12);
            s16x8 s0, s1;
            s0[0] = f2bf(va.x); s0[1] = f2bf(va.y); s0[2] = f2bf(va.z); s0[3] = f2bf(va.w);
            s0[4] = f2bf(vb.x); s0[5] = f2bf(vb.y); s0[6] = f2bf(vb.z); s0[7] = f2bf(vb.w);
            s1[0] = f2bf(vc.x); s1[1] = f2bf(vc.y); s1[2] = f2bf(vc.z); s1[3] = f2bf(vc.w);
            s1[4] = f2bf(vd.x); s1[5] = f2bf(vd.y); s1[6] = f2bf(vd.z); s1[7] = f2bf(vd.w);
            *(s16x8*)&Zb[q][mh] = s0;
            *(s16x8*)&Zb[q][mh + 8] = s1;
        }
        __syncthreads();
        s16x8 fr[8];
#pragma unroll
        for (int t = 0; t < 8; t++) fr[t] = *(s16x8*)&Zb[t * 16 + rw][kb * 8];
#pragma unroll
        for (int r = 0; r < 2; r++)
#pragma unroll
            for (int cc = 0; cc < 8; cc++)
                acc[r][cc] = __builtin_amdgcn_mfma_f32_16x16x32_bf16(
                    fr[2 * wid + r], fr[cc], acc[r][cc], 0, 0, 0);
    }
    float* sp = spart + ((size_t)mat * KS_COV + ks) * 16384;
#pragma unroll
    for (int r = 0; r < 2; r++)
#pragma unroll
        for (int cc = 0; cc < 8; cc++)
#pragma unroll
            for (int rr = 0; rr < 4; rr++) {
                int row = (2 * wid + r) * 16 + kb * 4 + rr;
                int col = cc * 16 + rw;
                sp[row * 128 + col] = acc[r][cc][rr];
            }
}

// ------------------------------------------------------------------
// K4: cov = S/M - mu mu^T  -> bf16. grid (16,8), block 256.
// ------------------------------------------------------------------
__global__ __launch_bounds__(256) void k_covfin(const float* __restrict__ spart,
                                                const float* __restrict__ mu,
                                                short* __restrict__ covbf) {
    int mat = blockIdx.x, seg = blockIdx.y;
    int e0 = (seg * 256 + threadIdx.x) * 8;
    const float* sp = spart + (size_t)mat * KS_COV * 16384;
    const float* mub = mu + mat * PD;
    float s[8];
#pragma unroll
    for (int u = 0; u < 8; u++) s[u] = 0.f;
#pragma unroll
    for (int k = 0; k < KS_COV; k++) {
        const float* b = sp + k * 16384 + e0;
        float4 u0 = *(const float4*)(b);
        float4 u1 = *(const float4*)(b + 4);
        s[0] += u0.x; s[1] += u0.y; s[2] += u0.z; s[3] += u0.w;
        s[4] += u1.x; s[5] += u1.y; s[6] += u1.z; s[7] += u1.w;
    }
    int i = e0 >> 7, j0 = e0 & 127;
    float mi = mub[i];
    s16x8 outv;
#pragma unroll
    for (int u = 0; u < 8; u++) {
        float c = s[u] * (1.0f / MROWS) - mi * mub[j0 + u];
        outv[u] = f2bf(c);
    }
    *(s16x8*)(covbf + (size_t)mat * 16384 + e0) = outv;
}

// ------------------------------------------------------------------
// K5: top-16 invariant subspace by orthogonal iteration.
// grid 16, block 512 (8 waves). A in bf16 LDS; matvec = 4 MFMA/wave.
// CholQR every 2 steps (wave-synchronous register Cholesky + ridge);
// final CholQR with fp32 Gram.
// ------------------------------------------------------------------
__global__ __launch_bounds__(512) void k_eigen(const short* __restrict__ covbf,
                                               float* __restrict__ U) {
    __shared__ short Abf[128][136];
    __shared__ short Qbf[16][136];
    __shared__ float Yt[16][132];
    __shared__ short Ybf[16][136];
    __shared__ float G[16][17];
    __shared__ float Lc[16][17];
    int mat = blockIdx.x, tid = threadIdx.x;
    int wid = tid >> 6, lane = tid & 63;
    int rw = lane & 15, kb = lane >> 4;
    {   // load A
        int row = tid >> 2, sg = (tid & 3) << 5;
        const short* src = covbf + (size_t)mat * 16384 + row * 128 + sg;
#pragma unroll
        for (int k = 0; k < 4; k++) *(s16x8*)&Abf[row][sg + 8 * k] = *(const s16x8*)(src + 8 * k);
    }
    {   // init Q (deterministic hash)
#pragma unroll
        for (int u = 0; u < 4; u++) {
            int e = tid * 4 + u;
            int j = e >> 7, m = e & 127;
            uint32_t x = (uint32_t)e ^ (0x9E3779B9u * (uint32_t)(mat + 1));
            x ^= x >> 16; x *= 0x7feb352du; x ^= x >> 15; x *= 0x846ca68bu; x ^= x >> 16;
            float v = (float)(int)x * 4.6566129e-10f;
            Qbf[j][m] = f2bf(v);
        }
    }
    for (int it = 0; it < NIT; it++) {
        __syncthreads();                       // Abf/Qbf ready
        // ---- matvec: wave wid computes rows 16*wid..16*wid+15
        f32x4 acc = (f32x4){0.f, 0.f, 0.f, 0.f};
#pragma unroll
        for (int kc = 0; kc < 4; kc++) {
            s16x8 a = *(s16x8*)&Abf[16 * wid + rw][kc * 32 + kb * 8];
            s16x8 b = *(s16x8*)&Qbf[rw][kc * 32 + kb * 8];
            acc = __builtin_amdgcn_mfma_f32_16x16x32_bf16(a, b, acc, 0, 0, 0);
        }
        *(f32x4*)&Yt[rw][16 * wid + kb * 4] = acc;   // Yt[col j][m]
        __syncthreads();                       // Yt ready
        bool fin = (it == NIT - 1);
        if ((it & 1) || fin) {
            if (!fin) {       // cvt Yt -> Ybf (all 512 threads)
                int j = tid >> 5, m4 = (tid & 31) << 2;
                float4 y = *(float4*)&Yt[j][m4];
                s16x4 sv; sv[0] = f2bf(y.x); sv[1] = f2bf(y.y); sv[2] = f2bf(y.z); sv[3] = f2bf(y.w);
                *(s16x4*)&Ybf[j][m4] = sv;
            }
            __syncthreads();
            if (!fin) {
                if (wid == 0) {   // G = Y^T Y via MFMA (bf16, mid-iteration)
                    f32x4 g = (f32x4){0.f, 0.f, 0.f, 0.f};
#pragma unroll
                    for (int kc = 0; kc < 4; kc++) {
                        s16x8 y = *(s16x8*)&Ybf[rw][kc * 32 + kb * 8];
                        g = __builtin_amdgcn_mfma_f32_16x16x32_bf16(y, y, g, 0, 0, 0);
                    }
#pragma unroll
                    for (int rr = 0; rr < 4; rr++) G[kb * 4 + rr][rw] = g[rr];
                }
            } else {
                if (tid < 256) {  // final: fp32 Gram
                    int i = tid >> 4, j = tid & 15;
                    float s = 0.f;
                    for (int mm = 0; mm < 128; mm += 4) {
                        float4 a = *(float4*)&Yt[i][mm];
                        float4 b = *(float4*)&Yt[j][mm];
                        s += a.x * b.x + a.y * b.y + a.z * b.z + a.w * b.w;
                    }
                    G[i][j] = s;
                }
            }
            __syncthreads();                   // G ready
            if (tid < 16) {                    // wave-synchronous Cholesky
                float g[16], Lr[16];
#pragma unroll
                for (int j = 0; j < 16; j++) g[j] = G[tid][j];
                float tr = g[tid];
#pragma unroll
                for (int off = 8; off > 0; off >>= 1) tr += __shfl_xor(tr, off);
                g[tid] += (fin ? 1e-6f : 0.03f) * (tr * (1.0f / 16.0f));  // ridge
#pragma unroll
                for (int j = 0; j < 16; j++) {
                    float s = g[j];
#pragma unroll
                    for (int k = 0; k < j; k++) s -= Lr[k] * __shfl(Lr[k], j);
                    float dj = __shfl(s, j);
                    float d = sqrtf(fmaxf(dj, 1e-20f));
                    Lr[j] = (tid == j) ? d : ((tid > j) ? s / d : 0.f);
                }
#pragma unroll
                for (int j = 0; j < 16; j++) Lc[tid][j] = Lr[j];
            }
            __syncthreads();                   // Lc ready
            if (tid < 128) {                   // trisolve: Q = Y L^-T, per column m
                int m = tid;
                float q[16];
#pragma unroll
                for (int j = 0; j < 16; j++) {
                    float s = Yt[j][m];
#pragma unroll
                    for (int k = 0; k < j; k++) s -= Lc[j][k] * q[k];
                    q[j] = s / Lc[j][j];
                }
                if (fin) {
                    float* ub = U + (size_t)mat * KSUB * PD;
#pragma unroll
                    for (int j = 0; j < 16; j++) ub[j * PD + m] = q[j];
                } else {
#pragma unroll
                    for (int j = 0; j < 16; j++) Qbf[j][m] = f2bf(q[j]);
                }
            }
        } else {   // no orth this step: Q <- bf16(Y)
            int j = tid >> 5, m4 = (tid & 31) << 2;
            float4 y = *(float4*)&Yt[j][m4];
            s16x4 sv; sv[0] = f2bf(y.x); sv[1] = f2bf(y.y); sv[2] = f2bf(y.z); sv[3] = f2bf(y.w);
            *(s16x4*)&Qbf[j][m4] = sv;
        }
    }
}

// ------------------------------------------------------------------
// K6: pairwise ||U_a^T U_b||_F^2. grid 114, block 256.
// blocks 0..65: teacher pairs a<b -> cross_gram; 66..113: (p,l) -> gram_sq
// ------------------------------------------------------------------
__global__ __launch_bounds__(256) void k_gram(const float* __restrict__ U,
                                              float* __restrict__ cross,
                                              float* __restrict__ gram) {
    __shared__ float red[256];
    int bid = blockIdx.x;
    int ma, mb; bool isCross;
    if (bid < 66) {
        int a = 0, rem = bid;
        while (rem >= 11 - a) { rem -= 11 - a; a++; }
        ma = a; mb = a + 1 + rem; isCross = true;
    } else {
        int idx = bid - 66;
        ma = 12 + idx / 12; mb = idx % 12; isCross = false;
    }
    int tid = threadIdx.x;
    int i = tid >> 4, j = tid & 15;
    const float* ua = U + ((size_t)ma * KSUB + i) * PD;
    const float* ub = U + ((size_t)mb * KSUB + j) * PD;
    float s = 0.f;
    for (int m = 0; m < PD; m += 4) {
        float4 x = *(const float4*)(ua + m);
        float4 y = *(const float4*)(ub + m);
        s += x.x * y.x + x.y * y.y + x.z * y.z + x.w * y.w;
    }
    red[tid] = s * s;
    __syncthreads();
    for (int st = 128; st > 0; st >>= 1) {
        if (tid < st) red[tid] += red[tid + st];
        __syncthreads();
    }
    if (tid == 0) {
        if (isCross) { cross[ma * L_T + mb] = red[0]; cross[mb * L_T + ma] = red[0]; }
        else gram[(ma - 12) * L_T + mb] = red[0];
    }
}

// ------------------------------------------------------------------
// K7: softmax weights + reg_loss. 1 block, 128 threads.
// ------------------------------------------------------------------
__global__ __launch_bounds__(128) void k_weights(const float* __restrict__ gram,
                                                 const float* __restrict__ cross,
                                                 const float* __restrict__ mu,
                                                 const float* __restrict__ logt,
                                                 float* __restrict__ w,
                                                 float* __restrict__ loss_out) {
    __shared__ float wsm[P_S][L_T];
    __shared__ float red[128];
    int tid = threadIdx.x;
    if (tid < P_S) {
        float tau = log1pf(expf(logt[tid]));
        float x[L_T];
        float mx = -1e30f;
#pragma unroll
        for (int l = 0; l < L_T; l++) {
            float d = 1.0f - gram[tid * L_T + l] * (1.0f / 16.0f);
            x[l] = -d / tau;
            mx = fmaxf(mx, x[l]);
        }
        float ssum = 0.f;
#pragma unroll
        for (int l = 0; l < L_T; l++) { x[l] = expf(x[l] - mx); ssum += x[l]; }
        float inv = 1.0f / ssum;
#pragma unroll
        for (int l = 0; l < L_T; l++) { float wv = x[l] * inv; wsm[tid][l] = wv; w[tid * L_T + l] = wv; }
    }
    __syncthreads();
    float racc = 0.f;
    {
        int q = tid;
#pragma unroll
        for (int p = 0; p < P_S; p++) {
            float zm = 0.f;
#pragma unroll
            for (int l = 0; l < L_T; l++) zm += wsm[p][l] * mu[l * PD + q];
            float d = zm - mu[(12 + p) * PD + q];
            racc += d * d;
        }
    }
    red[tid] = racc;
    __syncthreads();
    for (int st = 64; st > 0; st >>= 1) {
        if (tid < st) red[tid] += red[tid + st];
        __syncthreads();
    }
    if (tid == 0) {
        float recon = red[0] * (1.0f / PD);
        float orth = 0.f;
        for (int p = 0; p < P_S; p++)
            for (int a = 0; a < L_T; a++)
                for (int b = 0; b < L_T; b++)
                    if (a != b) orth += wsm[p][a] * wsm[p][b] * cross[a * L_T + b];
        orth *= 0.5f;
        loss_out[0] = 0.01f * orth / P_S + 0.01f * recon / P_S;
    }
}

// ------------------------------------------------------------------
// K8/K9: out[p][i] = sum_l w[p][l] * in[l][i], float4 grid-stride.
// ------------------------------------------------------------------
__global__ __launch_bounds__(256) void k_mix(const float* __restrict__ in,
                                             const float* __restrict__ w,
                                             float* __restrict__ out,
                                             int nv, size_t nl) {
    float wr[P_S][L_T];
#pragma unroll
    for (int p = 0; p < P_S; p++)
#pragma unroll
        for (int l = 0; l < L_T; l++) wr[p][l] = w[p * L_T + l];
    int stride = gridDim.x * blockDim.x;
    for (int v = blockIdx.x * blockDim.x + threadIdx.x; v < nv; v += stride) {
        size_t off = (size_t)v * 4;
        float4 o[P_S];
#pragma unroll
        for (int p = 0; p < P_S; p++) o[p] = make_float4(0.f, 0.f, 0.f, 0.f);
#pragma unroll
        for (int l = 0; l < L_T; l++) {
            float4 x = *(const float4*)(in + (size_t)l * nl + off);
#pragma unroll
            for (int p = 0; p < P_S; p++) {
                o[p].x += wr[p][l] * x.x; o[p].y += wr[p][l] * x.y;
                o[p].z += wr[p][l] * x.z; o[p].w += wr[p][l] * x.w;
            }
        }
#pragma unroll
        for (int p = 0; p < P_S; p++)
            *(float4*)(out + (size_t)p * nl + off) = o[p];
    }
}

extern "C" void kernel_launch(void* const* d_in, const int* in_sizes, int n_in,
                              void* d_out, int out_size, void* d_ws, size_t ws_size,
                              hipStream_t stream) {
    const float* student  = (const float*)d_in[0];
    const float* teacherT = (const float*)d_in[1];
    const float* teacherA = (const float*)d_in[2];
    const float* phis     = (const float*)d_in[3];
    const float* phit     = (const float*)d_in[4];
    const float* logt     = (const float*)d_in[5];
    float* out = (float*)d_out;

    char* ws = (char*)d_ws;
    float* zt    = (float*)(ws + ZT_B);
    float* sp    = (float*)(ws + SP_B);
    float* mu    = (float*)(ws + MU_B);
    short* covb  = (short*)(ws + COV_B);
    float* U     = (float*)(ws + U_B);
    float* cross = (float*)(ws + CROSS_B);
    float* gram  = (float*)(ws + GRAM_B);
    float* w     = (float*)(ws + W_B);

    k_zgemm<<<dim3(50, 12), 256, 0, stream>>>(teacherT, phit, zt, DT, 0);
    k_zgemm<<<dim3(50, 4), 256, 0, stream>>>(student, phis, zt, DS, 12);
    k_means<<<16, 1024, 0, stream>>>(zt, mu);
    k_covp<<<dim3(KS_COV, 16), 256, 0, stream>>>(zt, sp);
    k_covfin<<<dim3(16, 8), 256, 0, stream>>>(sp, mu, covb);
    k_eigen<<<16, 512, 0, stream>>>(covb, U);
    k_gram<<<114, 256, 0, stream>>>(U, cross, gram);
    k_weights<<<1, 128, 0, stream>>>(gram, cross, mu, logt, w, out + 78976512);

    const size_t NL_T = (size_t)MROWS * DT;           // 4,841,472
    const size_t NL_A = (size_t)32 * 12 * 197 * 197;  // 14,902,656
    k_mix<<<2048, 256, 0, stream>>>(teacherT, w, out, (int)(NL_T / 4), NL_T);
    k_mix<<<4096, 256, 0, stream>>>(teacherA, w, out + 19365888, (int)(NL_A / 4), NL_A);
}

// Round 3
// 722.501 us; speedup vs baseline: 3.5969x; 3.5969x over previous
//
#include <hip/hip_runtime.h>
#include <hip/hip_bf16.h>
#include <stdint.h>

typedef __attribute__((ext_vector_type(8))) short s16x8;
typedef __attribute__((ext_vector_type(4))) short s16x4;
typedef __attribute__((ext_vector_type(4))) float f32x4;

#define L_T 12
#define P_S 4
#define NMAT 16
#define MROWS 6304
#define PD 128
#define DT 768
#define DS 384
#define KSUB 16
#define KS_COV 8
#define NIT 48

// ---- workspace byte offsets (16B aligned) ----
#define ZB_B    0
#define SP_B    25821184
#define MU_B    34209792
#define COV_B   34217984
#define U_B     34742272
#define CROSS_B 34873344
#define GRAM_B  34873920
#define W_B     34874112
#define WHT_B   34874304
#define WLT_B   35070912
#define WHS_B   35267520
#define WLS_B   35365824

__device__ __forceinline__ short f2bf(float f) {
    __hip_bfloat16 h = __float2bfloat16(f);
    return *reinterpret_cast<short*>(&h);
}
__device__ __forceinline__ float bf2f(short s) {
    union { uint32_t u; float f; } c;
    c.u = ((uint32_t)(uint16_t)s) << 16;
    return c.f;
}
struct BfPair { short h, l; };
__device__ __forceinline__ BfPair split1(float x) {
    BfPair r;
    r.h = f2bf(x);
    r.l = f2bf(x - bf2f(r.h));
    return r;
}

// ------------------------------------------------------------------
// K0: pre-split phi weights into bf16 hi/lo (run once, tiny)
// ------------------------------------------------------------------
__global__ __launch_bounds__(256) void k_wsplit(const float* __restrict__ w,
                                                short* __restrict__ hi,
                                                short* __restrict__ lo, int n) {
    int e = (blockIdx.x * 256 + threadIdx.x) * 4;
    if (e >= n) return;
    float4 v = *(const float4*)(w + e);
    s16x4 h, l;
    BfPair p0 = split1(v.x), p1 = split1(v.y), p2 = split1(v.z), p3 = split1(v.w);
    h[0] = p0.h; l[0] = p0.l; h[1] = p1.h; l[1] = p1.l;
    h[2] = p2.h; l[2] = p2.l; h[3] = p3.h; l[3] = p3.l;
    *(s16x4*)(hi + e) = h;
    *(s16x4*)(lo + e) = l;
}

// ------------------------------------------------------------------
// K1: z = tokens @ phi^T via bf16 MFMA, hi/lo split (3 products).
// Output bf16, transposed: zbf[mat][q][m]. grid (50, nmat), block 256.
// ------------------------------------------------------------------
__global__ __launch_bounds__(256) void k_zgemm(const float* __restrict__ A,
                                               const short* __restrict__ whi,
                                               const short* __restrict__ wlo,
                                               short* __restrict__ zbf,
                                               int D, int matBase) {
    __shared__ short Ahi[128][40];
    __shared__ short Alo[128][40];
    __shared__ short Whs[128][40];
    __shared__ short Wls[128][40];
    int mat = matBase + blockIdx.y;
    const float* Ab = A + (size_t)blockIdx.y * MROWS * D;
    int m0 = blockIdx.x * 128;
    int tid = threadIdx.x;
    int wid = tid >> 6, lane = tid & 63;
    int rw = lane & 15, kb = lane >> 4;
    f32x4 acc[2][8];
#pragma unroll
    for (int r = 0; r < 2; r++)
#pragma unroll
        for (int c = 0; c < 8; c++) acc[r][c] = (f32x4){0.f, 0.f, 0.f, 0.f};

    for (int d0 = 0; d0 < D; d0 += 32) {
        __syncthreads();
        // stage A (fp32 -> hi/lo bf16): 128 rows x 32 cols
#pragma unroll
        for (int ii = 0; ii < 4; ii++) {
            int f = tid + 256 * ii;
            int row = f >> 3, c4 = (f & 7) << 2;
            int m = m0 + row;
            float4 v = make_float4(0.f, 0.f, 0.f, 0.f);
            if (m < MROWS) v = *(const float4*)(Ab + (size_t)m * D + d0 + c4);
            s16x4 h, l;
            BfPair p0 = split1(v.x), p1 = split1(v.y), p2 = split1(v.z), p3 = split1(v.w);
            h[0] = p0.h; l[0] = p0.l; h[1] = p1.h; l[1] = p1.l;
            h[2] = p2.h; l[2] = p2.l; h[3] = p3.h; l[3] = p3.l;
            *(s16x4*)&Ahi[row][c4] = h;
            *(s16x4*)&Alo[row][c4] = l;
        }
        // stage W (already bf16 hi/lo in global): 128 rows x 32 cols
#pragma unroll
        for (int ii = 0; ii < 2; ii++) {
            int f = tid + 256 * ii;
            int row = f >> 2, c8 = (f & 3) << 3;
            *(s16x8*)&Whs[row][c8] = *(const s16x8*)(whi + (size_t)row * D + d0 + c8);
            *(s16x8*)&Wls[row][c8] = *(const s16x8*)(wlo + (size_t)row * D + d0 + c8);
        }
        __syncthreads();
        s16x8 ah[2], al[2];
#pragma unroll
        for (int r = 0; r < 2; r++) {
            ah[r] = *(s16x8*)&Ahi[32 * wid + 16 * r + rw][kb * 8];
            al[r] = *(s16x8*)&Alo[32 * wid + 16 * r + rw][kb * 8];
        }
#pragma unroll
        for (int c = 0; c < 8; c++) {
            s16x8 wh = *(s16x8*)&Whs[16 * c + rw][kb * 8];
            s16x8 wl = *(s16x8*)&Wls[16 * c + rw][kb * 8];
#pragma unroll
            for (int r = 0; r < 2; r++) {
                acc[r][c] = __builtin_amdgcn_mfma_f32_16x16x32_bf16(ah[r], wh, acc[r][c], 0, 0, 0);
                acc[r][c] = __builtin_amdgcn_mfma_f32_16x16x32_bf16(al[r], wh, acc[r][c], 0, 0, 0);
                acc[r][c] = __builtin_amdgcn_mfma_f32_16x16x32_bf16(ah[r], wl, acc[r][c], 0, 0, 0);
            }
        }
    }
    // store bf16 transposed: D[m][q] -> zbf[q][m], 4 consecutive m per lane
    short* zb = zbf + (size_t)mat * PD * MROWS;
#pragma unroll
    for (int c = 0; c < 8; c++) {
        int q = 16 * c + rw;
#pragma unroll
        for (int r = 0; r < 2; r++) {
            int m = m0 + 32 * wid + 16 * r + 4 * kb;
            if (m < MROWS) {
                s16x4 o;
                o[0] = f2bf(acc[r][c][0]); o[1] = f2bf(acc[r][c][1]);
                o[2] = f2bf(acc[r][c][2]); o[3] = f2bf(acc[r][c][3]);
                *(s16x4*)(zb + (size_t)q * MROWS + m) = o;
            }
        }
    }
}

// ------------------------------------------------------------------
// K2: column means mu[mat][q] from bf16 z. grid (16,16), block 256.
// ------------------------------------------------------------------
__global__ __launch_bounds__(256) void k_means(const short* __restrict__ zbf,
                                               float* __restrict__ mu) {
    int mat = blockIdx.y;
    int q = blockIdx.x * 8 + (threadIdx.x >> 5);
    int sub = threadIdx.x & 31;
    const short* zr = zbf + (size_t)(mat * PD + q) * MROWS;
    float s = 0.f;
    for (int f = sub; f < MROWS / 8; f += 32) {
        s16x8 v = *(const s16x8*)(zr + 8 * f);
#pragma unroll
        for (int u = 0; u < 8; u++) s += bf2f(v[u]);
    }
#pragma unroll
    for (int off = 16; off > 0; off >>= 1) s += __shfl_xor(s, off);
    if (sub == 0) mu[mat * PD + q] = s * (1.0f / MROWS);
}

// ------------------------------------------------------------------
// K3: S-partials via bf16 MFMA. grid (KS_COV,16), block 256.
// ------------------------------------------------------------------
__global__ __launch_bounds__(256) void k_covp(const short* __restrict__ zbf,
                                              float* __restrict__ spart) {
    __shared__ short Zb[128][40];
    int mat = blockIdx.y, ks = blockIdx.x;
    int c0 = (ks * 197) / KS_COV, c1 = ((ks + 1) * 197) / KS_COV;
    int tid = threadIdx.x;
    int wid = tid >> 6, lane = tid & 63;
    int rw = lane & 15, kb = lane >> 4;
    f32x4 acc[2][8];
#pragma unroll
    for (int r = 0; r < 2; r++)
#pragma unroll
        for (int cc = 0; cc < 8; cc++) acc[r][cc] = (f32x4){0.f, 0.f, 0.f, 0.f};

    const short* zb = zbf + (size_t)mat * PD * MROWS;
    for (int c = c0; c < c1; c++) {
        int m0 = c * 32;
        __syncthreads();
        {
            int q = tid >> 1, mh = (tid & 1) << 4;
            const short* src = zb + (size_t)q * MROWS + m0 + mh;
            *(s16x8*)&Zb[q][mh] = *(const s16x8*)(src);
            *(s16x8*)&Zb[q][mh + 8] = *(const s16x8*)(src + 8);
        }
        __syncthreads();
        s16x8 fr[8];
#pragma unroll
        for (int t = 0; t < 8; t++) fr[t] = *(s16x8*)&Zb[t * 16 + rw][kb * 8];
#pragma unroll
        for (int r = 0; r < 2; r++)
#pragma unroll
            for (int cc = 0; cc < 8; cc++)
                acc[r][cc] = __builtin_amdgcn_mfma_f32_16x16x32_bf16(
                    fr[2 * wid + r], fr[cc], acc[r][cc], 0, 0, 0);
    }
    float* sp = spart + ((size_t)mat * KS_COV + ks) * 16384;
#pragma unroll
    for (int r = 0; r < 2; r++)
#pragma unroll
        for (int cc = 0; cc < 8; cc++)
#pragma unroll
            for (int rr = 0; rr < 4; rr++) {
                int row = (2 * wid + r) * 16 + kb * 4 + rr;
                int col = cc * 16 + rw;
                sp[row * 128 + col] = acc[r][cc][rr];
            }
}

// ------------------------------------------------------------------
// K4: cov = S/M - mu mu^T  -> bf16. grid (16,8), block 256.
// ------------------------------------------------------------------
__global__ __launch_bounds__(256) void k_covfin(const float* __restrict__ spart,
                                                const float* __restrict__ mu,
                                                short* __restrict__ covbf) {
    int mat = blockIdx.x, seg = blockIdx.y;
    int e0 = (seg * 256 + threadIdx.x) * 8;
    const float* sp = spart + (size_t)mat * KS_COV * 16384;
    const float* mub = mu + mat * PD;
    float s[8];
#pragma unroll
    for (int u = 0; u < 8; u++) s[u] = 0.f;
#pragma unroll
    for (int k = 0; k < KS_COV; k++) {
        const float* b = sp + k * 16384 + e0;
        float4 u0 = *(const float4*)(b);
        float4 u1 = *(const float4*)(b + 4);
        s[0] += u0.x; s[1] += u0.y; s[2] += u0.z; s[3] += u0.w;
        s[4] += u1.x; s[5] += u1.y; s[6] += u1.z; s[7] += u1.w;
    }
    int i = e0 >> 7, j0 = e0 & 127;
    float mi = mub[i];
    s16x8 outv;
#pragma unroll
    for (int u = 0; u < 8; u++) {
        float c = s[u] * (1.0f / MROWS) - mi * mub[j0 + u];
        outv[u] = f2bf(c);
    }
    *(s16x8*)(covbf + (size_t)mat * 16384 + e0) = outv;
}

// ------------------------------------------------------------------
// K5: top-16 invariant subspace by orthogonal iteration. grid 16, block 512.
// ------------------------------------------------------------------
__global__ __launch_bounds__(512) void k_eigen(const short* __restrict__ covbf,
                                               float* __restrict__ U) {
    __shared__ short Abf[128][136];
    __shared__ short Qbf[16][136];
    __shared__ float Yt[16][132];
    __shared__ short Ybf[16][136];
    __shared__ float G[16][17];
    __shared__ float Lc[16][17];
    int mat = blockIdx.x, tid = threadIdx.x;
    int wid = tid >> 6, lane = tid & 63;
    int rw = lane & 15, kb = lane >> 4;
    {   // load A
        int row = tid >> 2, sg = (tid & 3) << 5;
        const short* src = covbf + (size_t)mat * 16384 + row * 128 + sg;
#pragma unroll
        for (int k = 0; k < 4; k++) *(s16x8*)&Abf[row][sg + 8 * k] = *(const s16x8*)(src + 8 * k);
    }
    {   // init Q (deterministic hash)
#pragma unroll
        for (int u = 0; u < 4; u++) {
            int e = tid * 4 + u;
            int j = e >> 7, m = e & 127;
            uint32_t x = (uint32_t)e ^ (0x9E3779B9u * (uint32_t)(mat + 1));
            x ^= x >> 16; x *= 0x7feb352du; x ^= x >> 15; x *= 0x846ca68bu; x ^= x >> 16;
            float v = (float)(int)x * 4.6566129e-10f;
            Qbf[j][m] = f2bf(v);
        }
    }
    for (int it = 0; it < NIT; it++) {
        __syncthreads();
        f32x4 acc = (f32x4){0.f, 0.f, 0.f, 0.f};
#pragma unroll
        for (int kc = 0; kc < 4; kc++) {
            s16x8 a = *(s16x8*)&Abf[16 * wid + rw][kc * 32 + kb * 8];
            s16x8 b = *(s16x8*)&Qbf[rw][kc * 32 + kb * 8];
            acc = __builtin_amdgcn_mfma_f32_16x16x32_bf16(a, b, acc, 0, 0, 0);
        }
        *(f32x4*)&Yt[rw][16 * wid + kb * 4] = acc;
        __syncthreads();
        bool fin = (it == NIT - 1);
        if ((it & 1) || fin) {
            if (!fin) {
                int j = tid >> 5, m4 = (tid & 31) << 2;
                float4 y = *(float4*)&Yt[j][m4];
                s16x4 sv; sv[0] = f2bf(y.x); sv[1] = f2bf(y.y); sv[2] = f2bf(y.z); sv[3] = f2bf(y.w);
                *(s16x4*)&Ybf[j][m4] = sv;
            }
            __syncthreads();
            if (!fin) {
                if (wid == 0) {
                    f32x4 g = (f32x4){0.f, 0.f, 0.f, 0.f};
#pragma unroll
                    for (int kc = 0; kc < 4; kc++) {
                        s16x8 y = *(s16x8*)&Ybf[rw][kc * 32 + kb * 8];
                        g = __builtin_amdgcn_mfma_f32_16x16x32_bf16(y, y, g, 0, 0, 0);
                    }
#pragma unroll
                    for (int rr = 0; rr < 4; rr++) G[kb * 4 + rr][rw] = g[rr];
                }
            } else {
                if (tid < 256) {
                    int i = tid >> 4, j = tid & 15;
                    float s = 0.f;
                    for (int mm = 0; mm < 128; mm += 4) {
                        float4 a = *(float4*)&Yt[i][mm];
                        float4 b = *(float4*)&Yt[j][mm];
                        s += a.x * b.x + a.y * b.y + a.z * b.z + a.w * b.w;
                    }
                    G[i][j] = s;
                }
            }
            __syncthreads();
            if (tid < 16) {
                float g[16], Lr[16];
#pragma unroll
                for (int j = 0; j < 16; j++) g[j] = G[tid][j];
                float tr = g[tid];
#pragma unroll
                for (int off = 8; off > 0; off >>= 1) tr += __shfl_xor(tr, off);
                g[tid] += (fin ? 1e-6f : 0.03f) * (tr * (1.0f / 16.0f));
#pragma unroll
                for (int j = 0; j < 16; j++) {
                    float s = g[j];
#pragma unroll
                    for (int k = 0; k < j; k++) s -= Lr[k] * __shfl(Lr[k], j);
                    float dj = __shfl(s, j);
                    float d = sqrtf(fmaxf(dj, 1e-20f));
                    Lr[j] = (tid == j) ? d : ((tid > j) ? s / d : 0.f);
                }
#pragma unroll
                for (int j = 0; j < 16; j++) Lc[tid][j] = Lr[j];
            }
            __syncthreads();
            if (tid < 128) {
                int m = tid;
                float q[16];
#pragma unroll
                for (int j = 0; j < 16; j++) {
                    float s = Yt[j][m];
#pragma unroll
                    for (int k = 0; k < j; k++) s -= Lc[j][k] * q[k];
                    q[j] = s / Lc[j][j];
                }
                if (fin) {
                    float* ub = U + (size_t)mat * KSUB * PD;
#pragma unroll
                    for (int j = 0; j < 16; j++) ub[j * PD + m] = q[j];
                } else {
#pragma unroll
                    for (int j = 0; j < 16; j++) Qbf[j][m] = f2bf(q[j]);
                }
            }
        } else {
            int j = tid >> 5, m4 = (tid & 31) << 2;
            float4 y = *(float4*)&Yt[j][m4];
            s16x4 sv; sv[0] = f2bf(y.x); sv[1] = f2bf(y.y); sv[2] = f2bf(y.z); sv[3] = f2bf(y.w);
            *(s16x4*)&Qbf[j][m4] = sv;
        }
    }
}

// ------------------------------------------------------------------
// K6: pairwise ||U_a^T U_b||_F^2. grid 114, block 256.
// ------------------------------------------------------------------
__global__ __launch_bounds__(256) void k_gram(const float* __restrict__ U,
                                              float* __restrict__ cross,
                                              float* __restrict__ gram) {
    __shared__ float red[256];
    int bid = blockIdx.x;
    int ma, mb; bool isCross;
    if (bid < 66) {
        int a = 0, rem = bid;
        while (rem >= 11 - a) { rem -= 11 - a; a++; }
        ma = a; mb = a + 1 + rem; isCross = true;
    } else {
        int idx = bid - 66;
        ma = 12 + idx / 12; mb = idx % 12; isCross = false;
    }
    int tid = threadIdx.x;
    int i = tid >> 4, j = tid & 15;
    const float* ua = U + ((size_t)ma * KSUB + i) * PD;
    const float* ub = U + ((size_t)mb * KSUB + j) * PD;
    float s = 0.f;
    for (int m = 0; m < PD; m += 4) {
        float4 x = *(const float4*)(ua + m);
        float4 y = *(const float4*)(ub + m);
        s += x.x * y.x + x.y * y.y + x.z * y.z + x.w * y.w;
    }
    red[tid] = s * s;
    __syncthreads();
    for (int st = 128; st > 0; st >>= 1) {
        if (tid < st) red[tid] += red[tid + st];
        __syncthreads();
    }
    if (tid == 0) {
        if (isCross) { cross[ma * L_T + mb] = red[0]; cross[mb * L_T + ma] = red[0]; }
        else gram[(ma - 12) * L_T + mb] = red[0];
    }
}

// ------------------------------------------------------------------
// K7: softmax weights + reg_loss. 1 block, 128 threads.
// ------------------------------------------------------------------
__global__ __launch_bounds__(128) void k_weights(const float* __restrict__ gram,
                                                 const float* __restrict__ cross,
                                                 const float* __restrict__ mu,
                                                 const float* __restrict__ logt,
                                                 float* __restrict__ w,
                                                 float* __restrict__ loss_out) {
    __shared__ float wsm[P_S][L_T];
    __shared__ float red[128];
    int tid = threadIdx.x;
    if (tid < P_S) {
        float tau = log1pf(expf(logt[tid]));
        float x[L_T];
        float mx = -1e30f;
#pragma unroll
        for (int l = 0; l < L_T; l++) {
            float d = 1.0f - gram[tid * L_T + l] * (1.0f / 16.0f);
            x[l] = -d / tau;
            mx = fmaxf(mx, x[l]);
        }
        float ssum = 0.f;
#pragma unroll
        for (int l = 0; l < L_T; l++) { x[l] = expf(x[l] - mx); ssum += x[l]; }
        float inv = 1.0f / ssum;
#pragma unroll
        for (int l = 0; l < L_T; l++) { float wv = x[l] * inv; wsm[tid][l] = wv; w[tid * L_T + l] = wv; }
    }
    __syncthreads();
    float racc = 0.f;
    {
        int q = tid;
#pragma unroll
        for (int p = 0; p < P_S; p++) {
            float zm = 0.f;
#pragma unroll
            for (int l = 0; l < L_T; l++) zm += wsm[p][l] * mu[l * PD + q];
            float d = zm - mu[(12 + p) * PD + q];
            racc += d * d;
        }
    }
    red[tid] = racc;
    __syncthreads();
    for (int st = 64; st > 0; st >>= 1) {
        if (tid < st) red[tid] += red[tid + st];
        __syncthreads();
    }
    if (tid == 0) {
        float recon = red[0] * (1.0f / PD);
        float orth = 0.f;
        for (int p = 0; p < P_S; p++)
            for (int a = 0; a < L_T; a++)
                for (int b = 0; b < L_T; b++)
                    if (a != b) orth += wsm[p][a] * wsm[p][b] * cross[a * L_T + b];
        orth *= 0.5f;
        loss_out[0] = 0.01f * orth / P_S + 0.01f * recon / P_S;
    }
}

// ------------------------------------------------------------------
// K8/K9: out[p][i] = sum_l w[p][l] * in[l][i], float4 grid-stride.
// ------------------------------------------------------------------
__global__ __launch_bounds__(256) void k_mix(const float* __restrict__ in,
                                             const float* __restrict__ w,
                                             float* __restrict__ out,
                                             int nv, size_t nl) {
    float wr[P_S][L_T];
#pragma unroll
    for (int p = 0; p < P_S; p++)
#pragma unroll
        for (int l = 0; l < L_T; l++) wr[p][l] = w[p * L_T + l];
    int stride = gridDim.x * blockDim.x;
    for (int v = blockIdx.x * blockDim.x + threadIdx.x; v < nv; v += stride) {
        size_t off = (size_t)v * 4;
        float4 o[P_S];
#pragma unroll
        for (int p = 0; p < P_S; p++) o[p] = make_float4(0.f, 0.f, 0.f, 0.f);
#pragma unroll
        for (int l = 0; l < L_T; l++) {
            float4 x = *(const float4*)(in + (size_t)l * nl + off);
#pragma unroll
            for (int p = 0; p < P_S; p++) {
                o[p].x += wr[p][l] * x.x; o[p].y += wr[p][l] * x.y;
                o[p].z += wr[p][l] * x.z; o[p].w += wr[p][l] * x.w;
            }
        }
#pragma unroll
        for (int p = 0; p < P_S; p++)
            *(float4*)(out + (size_t)p * nl + off) = o[p];
    }
}

extern "C" void kernel_launch(void* const* d_in, const int* in_sizes, int n_in,
                              void* d_out, int out_size, void* d_ws, size_t ws_size,
                              hipStream_t stream) {
    const float* student  = (const float*)d_in[0];
    const float* teacherT = (const float*)d_in[1];
    const float* teacherA = (const float*)d_in[2];
    const float* phis     = (const float*)d_in[3];
    const float* phit     = (const float*)d_in[4];
    const float* logt     = (const float*)d_in[5];
    float* out = (float*)d_out;

    char* ws = (char*)d_ws;
    short* zbf   = (short*)(ws + ZB_B);
    float* sp    = (float*)(ws + SP_B);
    float* mu    = (float*)(ws + MU_B);
    short* covb  = (short*)(ws + COV_B);
    float* U     = (float*)(ws + U_B);
    float* cross = (float*)(ws + CROSS_B);
    float* gram  = (float*)(ws + GRAM_B);
    float* w     = (float*)(ws + W_B);
    short* whiT  = (short*)(ws + WHT_B);
    short* wloT  = (short*)(ws + WLT_B);
    short* whiS  = (short*)(ws + WHS_B);
    short* wloS  = (short*)(ws + WLS_B);

    k_wsplit<<<96, 256, 0, stream>>>(phit, whiT, wloT, PD * DT);
    k_wsplit<<<48, 256, 0, stream>>>(phis, whiS, wloS, PD * DS);
    k_zgemm<<<dim3(50, 12), 256, 0, stream>>>(teacherT, whiT, wloT, zbf, DT, 0);
    k_zgemm<<<dim3(50, 4), 256, 0, stream>>>(student, whiS, wloS, zbf, DS, 12);
    k_means<<<dim3(16, 16), 256, 0, stream>>>(zbf, mu);
    k_covp<<<dim3(KS_COV, 16), 256, 0, stream>>>(zbf, sp);
    k_covfin<<<dim3(16, 8), 256, 0, stream>>>(sp, mu, covb);
    k_eigen<<<16, 512, 0, stream>>>(covb, U);
    k_gram<<<114, 256, 0, stream>>>(U, cross, gram);
    k_weights<<<1, 128, 0, stream>>>(gram, cross, mu, logt, w, out + 78976512);

    const size_t NL_T = (size_t)MROWS * DT;           // 4,841,472
    const size_t NL_A = (size_t)32 * 12 * 197 * 197;  // 14,902,656
    k_mix<<<2048, 256, 0, stream>>>(teacherT, w, out, (int)(NL_T / 4), NL_T);
    k_mix<<<4096, 256, 0, stream>>>(teacherA, w, out + 19365888, (int)(NL_A / 4), NL_A);
}

// Round 4
// 697.789 us; speedup vs baseline: 3.7243x; 1.0354x over previous
//
#include <hip/hip_runtime.h>
#include <hip/hip_bf16.h>
#include <stdint.h>

typedef __attribute__((ext_vector_type(8))) short s16x8;
typedef __attribute__((ext_vector_type(4))) short s16x4;
typedef __attribute__((ext_vector_type(4))) float f32x4;

#define L_T 12
#define P_S 4
#define NMAT 16
#define MROWS 6304
#define PD 128
#define DT 768
#define DS 384
#define KSUB 16
#define KS_COV 8
#define NIT 48

// ---- workspace byte offsets (16B aligned) ----
#define ZB_B    0
#define SP_B    25821184
#define MU_B    34209792
#define COV_B   34217984
#define U_B     34742272
#define CROSS_B 34873344
#define GRAM_B  34873920
#define W_B     34874112

__device__ __forceinline__ short f2bf(float f) {
    __hip_bfloat16 h = __float2bfloat16(f);
    return *reinterpret_cast<short*>(&h);
}
__device__ __forceinline__ float bf2f(short s) {
    union { uint32_t u; float f; } c;
    c.u = ((uint32_t)(uint16_t)s) << 16;
    return c.f;
}

// ------------------------------------------------------------------
// K1: z = tokens @ phi^T via single-product bf16 MFMA.
// Output bf16, transposed: zbf[mat][q][m]. grid (50, nmat), block 256.
// ------------------------------------------------------------------
__global__ __launch_bounds__(256) void k_zgemm(const float* __restrict__ A,
                                               const float* __restrict__ W,
                                               short* __restrict__ zbf,
                                               int D, int matBase) {
    __shared__ short As[128][40];
    __shared__ short Ws[128][40];
    int mat = matBase + blockIdx.y;
    const float* Ab = A + (size_t)blockIdx.y * MROWS * D;
    int m0 = blockIdx.x * 128;
    int tid = threadIdx.x;
    int wid = tid >> 6, lane = tid & 63;
    int rw = lane & 15, kb = lane >> 4;
    f32x4 acc[2][8];
#pragma unroll
    for (int r = 0; r < 2; r++)
#pragma unroll
        for (int c = 0; c < 8; c++) acc[r][c] = (f32x4){0.f, 0.f, 0.f, 0.f};

    for (int d0 = 0; d0 < D; d0 += 32) {
        __syncthreads();
        // stage A tile (fp32 -> bf16): 128 rows x 32 cols
#pragma unroll
        for (int ii = 0; ii < 4; ii++) {
            int f = tid + 256 * ii;
            int row = f >> 3, c4 = (f & 7) << 2;
            int m = m0 + row;
            float4 v = make_float4(0.f, 0.f, 0.f, 0.f);
            if (m < MROWS) v = *(const float4*)(Ab + (size_t)m * D + d0 + c4);
            s16x4 h;
            h[0] = f2bf(v.x); h[1] = f2bf(v.y); h[2] = f2bf(v.z); h[3] = f2bf(v.w);
            *(s16x4*)&As[row][c4] = h;
        }
        // stage W tile (fp32 -> bf16): 128 rows x 32 cols
#pragma unroll
        for (int ii = 0; ii < 4; ii++) {
            int f = tid + 256 * ii;
            int row = f >> 3, c4 = (f & 7) << 2;
            float4 v = *(const float4*)(W + (size_t)row * D + d0 + c4);
            s16x4 h;
            h[0] = f2bf(v.x); h[1] = f2bf(v.y); h[2] = f2bf(v.z); h[3] = f2bf(v.w);
            *(s16x4*)&Ws[row][c4] = h;
        }
        __syncthreads();
        s16x8 ah[2];
#pragma unroll
        for (int r = 0; r < 2; r++)
            ah[r] = *(s16x8*)&As[32 * wid + 16 * r + rw][kb * 8];
#pragma unroll
        for (int c = 0; c < 8; c++) {
            s16x8 wv = *(s16x8*)&Ws[16 * c + rw][kb * 8];
#pragma unroll
            for (int r = 0; r < 2; r++)
                acc[r][c] = __builtin_amdgcn_mfma_f32_16x16x32_bf16(ah[r], wv, acc[r][c], 0, 0, 0);
        }
    }
    // store bf16 transposed: D[m][q] -> zbf[q][m], 4 consecutive m per lane
    short* zb = zbf + (size_t)mat * PD * MROWS;
#pragma unroll
    for (int c = 0; c < 8; c++) {
        int q = 16 * c + rw;
#pragma unroll
        for (int r = 0; r < 2; r++) {
            int m = m0 + 32 * wid + 16 * r + 4 * kb;
            if (m < MROWS) {
                s16x4 o;
                o[0] = f2bf(acc[r][c][0]); o[1] = f2bf(acc[r][c][1]);
                o[2] = f2bf(acc[r][c][2]); o[3] = f2bf(acc[r][c][3]);
                *(s16x4*)(zb + (size_t)q * MROWS + m) = o;
            }
        }
    }
}

// ------------------------------------------------------------------
// K2: column means mu[mat][q] from bf16 z. grid (16,16), block 256.
// ------------------------------------------------------------------
__global__ __launch_bounds__(256) void k_means(const short* __restrict__ zbf,
                                               float* __restrict__ mu) {
    int mat = blockIdx.y;
    int q = blockIdx.x * 8 + (threadIdx.x >> 5);
    int sub = threadIdx.x & 31;
    const short* zr = zbf + (size_t)(mat * PD + q) * MROWS;
    float s = 0.f;
    for (int f = sub; f < MROWS / 8; f += 32) {
        s16x8 v = *(const s16x8*)(zr + 8 * f);
#pragma unroll
        for (int u = 0; u < 8; u++) s += bf2f(v[u]);
    }
#pragma unroll
    for (int off = 16; off > 0; off >>= 1) s += __shfl_xor(s, off);
    if (sub == 0) mu[mat * PD + q] = s * (1.0f / MROWS);
}

// ------------------------------------------------------------------
// K3: S-partials via bf16 MFMA. grid (KS_COV,16), block 256.
// ------------------------------------------------------------------
__global__ __launch_bounds__(256) void k_covp(const short* __restrict__ zbf,
                                              float* __restrict__ spart) {
    __shared__ short Zb[128][40];
    int mat = blockIdx.y, ks = blockIdx.x;
    int c0 = (ks * 197) / KS_COV, c1 = ((ks + 1) * 197) / KS_COV;
    int tid = threadIdx.x;
    int wid = tid >> 6, lane = tid & 63;
    int rw = lane & 15, kb = lane >> 4;
    f32x4 acc[2][8];
#pragma unroll
    for (int r = 0; r < 2; r++)
#pragma unroll
        for (int cc = 0; cc < 8; cc++) acc[r][cc] = (f32x4){0.f, 0.f, 0.f, 0.f};

    const short* zb = zbf + (size_t)mat * PD * MROWS;
    for (int c = c0; c < c1; c++) {
        int m0 = c * 32;
        __syncthreads();
        {
            int q = tid >> 1, mh = (tid & 1) << 4;
            const short* src = zb + (size_t)q * MROWS + m0 + mh;
            *(s16x8*)&Zb[q][mh] = *(const s16x8*)(src);
            *(s16x8*)&Zb[q][mh + 8] = *(const s16x8*)(src + 8);
        }
        __syncthreads();
        s16x8 fr[8];
#pragma unroll
        for (int t = 0; t < 8; t++) fr[t] = *(s16x8*)&Zb[t * 16 + rw][kb * 8];
#pragma unroll
        for (int r = 0; r < 2; r++)
#pragma unroll
            for (int cc = 0; cc < 8; cc++)
                acc[r][cc] = __builtin_amdgcn_mfma_f32_16x16x32_bf16(
                    fr[2 * wid + r], fr[cc], acc[r][cc], 0, 0, 0);
    }
    float* sp = spart + ((size_t)mat * KS_COV + ks) * 16384;
#pragma unroll
    for (int r = 0; r < 2; r++)
#pragma unroll
        for (int cc = 0; cc < 8; cc++)
#pragma unroll
            for (int rr = 0; rr < 4; rr++) {
                int row = (2 * wid + r) * 16 + kb * 4 + rr;
                int col = cc * 16 + rw;
                sp[row * 128 + col] = acc[r][cc][rr];
            }
}

// ------------------------------------------------------------------
// K4: cov = S/M - mu mu^T  -> bf16. grid (16,8), block 256.
// ------------------------------------------------------------------
__global__ __launch_bounds__(256) void k_covfin(const float* __restrict__ spart,
                                                const float* __restrict__ mu,
                                                short* __restrict__ covbf) {
    int mat = blockIdx.x, seg = blockIdx.y;
    int e0 = (seg * 256 + threadIdx.x) * 8;
    const float* sp = spart + (size_t)mat * KS_COV * 16384;
    const float* mub = mu + mat * PD;
    float s[8];
#pragma unroll
    for (int u = 0; u < 8; u++) s[u] = 0.f;
#pragma unroll
    for (int k = 0; k < KS_COV; k++) {
        const float* b = sp + k * 16384 + e0;
        float4 u0 = *(const float4*)(b);
        float4 u1 = *(const float4*)(b + 4);
        s[0] += u0.x; s[1] += u0.y; s[2] += u0.z; s[3] += u0.w;
        s[4] += u1.x; s[5] += u1.y; s[6] += u1.z; s[7] += u1.w;
    }
    int i = e0 >> 7, j0 = e0 & 127;
    float mi = mub[i];
    s16x8 outv;
#pragma unroll
    for (int u = 0; u < 8; u++) {
        float c = s[u] * (1.0f / MROWS) - mi * mub[j0 + u];
        outv[u] = f2bf(c);
    }
    *(s16x8*)(covbf + (size_t)mat * 16384 + e0) = outv;
}

// ------------------------------------------------------------------
// K5: top-16 invariant subspace by orthogonal iteration. grid 16, block 512.
// ------------------------------------------------------------------
__global__ __launch_bounds__(512) void k_eigen(const short* __restrict__ covbf,
                                               float* __restrict__ U) {
    __shared__ short Abf[128][136];
    __shared__ short Qbf[16][136];
    __shared__ float Yt[16][132];
    __shared__ short Ybf[16][136];
    __shared__ float G[16][17];
    __shared__ float Lc[16][17];
    int mat = blockIdx.x, tid = threadIdx.x;
    int wid = tid >> 6, lane = tid & 63;
    int rw = lane & 15, kb = lane >> 4;
    {   // load A
        int row = tid >> 2, sg = (tid & 3) << 5;
        const short* src = covbf + (size_t)mat * 16384 + row * 128 + sg;
#pragma unroll
        for (int k = 0; k < 4; k++) *(s16x8*)&Abf[row][sg + 8 * k] = *(const s16x8*)(src + 8 * k);
    }
    {   // init Q (deterministic hash)
#pragma unroll
        for (int u = 0; u < 4; u++) {
            int e = tid * 4 + u;
            int j = e >> 7, m = e & 127;
            uint32_t x = (uint32_t)e ^ (0x9E3779B9u * (uint32_t)(mat + 1));
            x ^= x >> 16; x *= 0x7feb352du; x ^= x >> 15; x *= 0x846ca68bu; x ^= x >> 16;
            float v = (float)(int)x * 4.6566129e-10f;
            Qbf[j][m] = f2bf(v);
        }
    }
    for (int it = 0; it < NIT; it++) {
        __syncthreads();
        f32x4 acc = (f32x4){0.f, 0.f, 0.f, 0.f};
#pragma unroll
        for (int kc = 0; kc < 4; kc++) {
            s16x8 a = *(s16x8*)&Abf[16 * wid + rw][kc * 32 + kb * 8];
            s16x8 b = *(s16x8*)&Qbf[rw][kc * 32 + kb * 8];
            acc = __builtin_amdgcn_mfma_f32_16x16x32_bf16(a, b, acc, 0, 0, 0);
        }
        *(f32x4*)&Yt[rw][16 * wid + kb * 4] = acc;
        __syncthreads();
        bool fin = (it == NIT - 1);
        if ((it & 1) || fin) {
            if (!fin) {
                int j = tid >> 5, m4 = (tid & 31) << 2;
                float4 y = *(float4*)&Yt[j][m4];
                s16x4 sv; sv[0] = f2bf(y.x); sv[1] = f2bf(y.y); sv[2] = f2bf(y.z); sv[3] = f2bf(y.w);
                *(s16x4*)&Ybf[j][m4] = sv;
            }
            __syncthreads();
            if (!fin) {
                if (wid == 0) {
                    f32x4 g = (f32x4){0.f, 0.f, 0.f, 0.f};
#pragma unroll
                    for (int kc = 0; kc < 4; kc++) {
                        s16x8 y = *(s16x8*)&Ybf[rw][kc * 32 + kb * 8];
                        g = __builtin_amdgcn_mfma_f32_16x16x32_bf16(y, y, g, 0, 0, 0);
                    }
#pragma unroll
                    for (int rr = 0; rr < 4; rr++) G[kb * 4 + rr][rw] = g[rr];
                }
            } else {
                if (tid < 256) {
                    int i = tid >> 4, j = tid & 15;
                    float s = 0.f;
                    for (int mm = 0; mm < 128; mm += 4) {
                        float4 a = *(float4*)&Yt[i][mm];
                        float4 b = *(float4*)&Yt[j][mm];
                        s += a.x * b.x + a.y * b.y + a.z * b.z + a.w * b.w;
                    }
                    G[i][j] = s;
                }
            }
            __syncthreads();
            if (tid < 16) {
                float g[16], Lr[16];
#pragma unroll
                for (int j = 0; j < 16; j++) g[j] = G[tid][j];
                float tr = g[tid];
#pragma unroll
                for (int off = 8; off > 0; off >>= 1) tr += __shfl_xor(tr, off);
                g[tid] += (fin ? 1e-6f : 0.03f) * (tr * (1.0f / 16.0f));
#pragma unroll
                for (int j = 0; j < 16; j++) {
                    float s = g[j];
#pragma unroll
                    for (int k = 0; k < j; k++) s -= Lr[k] * __shfl(Lr[k], j);
                    float dj = __shfl(s, j);
                    float d = sqrtf(fmaxf(dj, 1e-20f));
                    Lr[j] = (tid == j) ? d : ((tid > j) ? s / d : 0.f);
                }
#pragma unroll
                for (int j = 0; j < 16; j++) Lc[tid][j] = Lr[j];
            }
            __syncthreads();
            if (tid < 128) {
                int m = tid;
                float q[16];
#pragma unroll
                for (int j = 0; j < 16; j++) {
                    float s = Yt[j][m];
#pragma unroll
                    for (int k = 0; k < j; k++) s -= Lc[j][k] * q[k];
                    q[j] = s / Lc[j][j];
                }
                if (fin) {
                    float* ub = U + (size_t)mat * KSUB * PD;
#pragma unroll
                    for (int j = 0; j < 16; j++) ub[j * PD + m] = q[j];
                } else {
#pragma unroll
                    for (int j = 0; j < 16; j++) Qbf[j][m] = f2bf(q[j]);
                }
            }
        } else {
            int j = tid >> 5, m4 = (tid & 31) << 2;
            float4 y = *(float4*)&Yt[j][m4];
            s16x4 sv; sv[0] = f2bf(y.x); sv[1] = f2bf(y.y); sv[2] = f2bf(y.z); sv[3] = f2bf(y.w);
            *(s16x4*)&Qbf[j][m4] = sv;
        }
    }
}

// ------------------------------------------------------------------
// K6: pairwise ||U_a^T U_b||_F^2. grid 114, block 256.
// ------------------------------------------------------------------
__global__ __launch_bounds__(256) void k_gram(const float* __restrict__ U,
                                              float* __restrict__ cross,
                                              float* __restrict__ gram) {
    __shared__ float red[256];
    int bid = blockIdx.x;
    int ma, mb; bool isCross;
    if (bid < 66) {
        int a = 0, rem = bid;
        while (rem >= 11 - a) { rem -= 11 - a; a++; }
        ma = a; mb = a + 1 + rem; isCross = true;
    } else {
        int idx = bid - 66;
        ma = 12 + idx / 12; mb = idx % 12; isCross = false;
    }
    int tid = threadIdx.x;
    int i = tid >> 4, j = tid & 15;
    const float* ua = U + ((size_t)ma * KSUB + i) * PD;
    const float* ub = U + ((size_t)mb * KSUB + j) * PD;
    float s = 0.f;
    for (int m = 0; m < PD; m += 4) {
        float4 x = *(const float4*)(ua + m);
        float4 y = *(const float4*)(ub + m);
        s += x.x * y.x + x.y * y.y + x.z * y.z + x.w * y.w;
    }
    red[tid] = s * s;
    __syncthreads();
    for (int st = 128; st > 0; st >>= 1) {
        if (tid < st) red[tid] += red[tid + st];
        __syncthreads();
    }
    if (tid == 0) {
        if (isCross) { cross[ma * L_T + mb] = red[0]; cross[mb * L_T + ma] = red[0]; }
        else gram[(ma - 12) * L_T + mb] = red[0];
    }
}

// ------------------------------------------------------------------
// K7: softmax weights + reg_loss. 1 block, 128 threads.
// ------------------------------------------------------------------
__global__ __launch_bounds__(128) void k_weights(const float* __restrict__ gram,
                                                 const float* __restrict__ cross,
                                                 const float* __restrict__ mu,
                                                 const float* __restrict__ logt,
                                                 float* __restrict__ w,
                                                 float* __restrict__ loss_out) {
    __shared__ float wsm[P_S][L_T];
    __shared__ float red[128];
    int tid = threadIdx.x;
    if (tid < P_S) {
        float tau = log1pf(expf(logt[tid]));
        float x[L_T];
        float mx = -1e30f;
#pragma unroll
        for (int l = 0; l < L_T; l++) {
            float d = 1.0f - gram[tid * L_T + l] * (1.0f / 16.0f);
            x[l] = -d / tau;
            mx = fmaxf(mx, x[l]);
        }
        float ssum = 0.f;
#pragma unroll
        for (int l = 0; l < L_T; l++) { x[l] = expf(x[l] - mx); ssum += x[l]; }
        float inv = 1.0f / ssum;
#pragma unroll
        for (int l = 0; l < L_T; l++) { float wv = x[l] * inv; wsm[tid][l] = wv; w[tid * L_T + l] = wv; }
    }
    __syncthreads();
    float racc = 0.f;
    {
        int q = tid;
#pragma unroll
        for (int p = 0; p < P_S; p++) {
            float zm = 0.f;
#pragma unroll
            for (int l = 0; l < L_T; l++) zm += wsm[p][l] * mu[l * PD + q];
            float d = zm - mu[(12 + p) * PD + q];
            racc += d * d;
        }
    }
    red[tid] = racc;
    __syncthreads();
    for (int st = 64; st > 0; st >>= 1) {
        if (tid < st) red[tid] += red[tid + st];
        __syncthreads();
    }
    if (tid == 0) {
        float recon = red[0] * (1.0f / PD);
        float orth = 0.f;
        for (int p = 0; p < P_S; p++)
            for (int a = 0; a < L_T; a++)
                for (int b = 0; b < L_T; b++)
                    if (a != b) orth += wsm[p][a] * wsm[p][b] * cross[a * L_T + b];
        orth *= 0.5f;
        loss_out[0] = 0.01f * orth / P_S + 0.01f * recon / P_S;
    }
}

// ------------------------------------------------------------------
// K8/K9: out[p][i] = sum_l w[p][l] * in[l][i], float4 grid-stride.
// ------------------------------------------------------------------
__global__ __launch_bounds__(256) void k_mix(const float* __restrict__ in,
                                             const float* __restrict__ w,
                                             float* __restrict__ out,
                                             int nv, size_t nl) {
    float wr[P_S][L_T];
#pragma unroll
    for (int p = 0; p < P_S; p++)
#pragma unroll
        for (int l = 0; l < L_T; l++) wr[p][l] = w[p * L_T + l];
    int stride = gridDim.x * blockDim.x;
    for (int v = blockIdx.x * blockDim.x + threadIdx.x; v < nv; v += stride) {
        size_t off = (size_t)v * 4;
        float4 o[P_S];
#pragma unroll
        for (int p = 0; p < P_S; p++) o[p] = make_float4(0.f, 0.f, 0.f, 0.f);
#pragma unroll
        for (int l = 0; l < L_T; l++) {
            float4 x = *(const float4*)(in + (size_t)l * nl + off);
#pragma unroll
            for (int p = 0; p < P_S; p++) {
                o[p].x += wr[p][l] * x.x; o[p].y += wr[p][l] * x.y;
                o[p].z += wr[p][l] * x.z; o[p].w += wr[p][l] * x.w;
            }
        }
#pragma unroll
        for (int p = 0; p < P_S; p++)
            *(float4*)(out + (size_t)p * nl + off) = o[p];
    }
}

extern "C" void kernel_launch(void* const* d_in, const int* in_sizes, int n_in,
                              void* d_out, int out_size, void* d_ws, size_t ws_size,
                              hipStream_t stream) {
    const float* student  = (const float*)d_in[0];
    const float* teacherT = (const float*)d_in[1];
    const float* teacherA = (const float*)d_in[2];
    const float* phis     = (const float*)d_in[3];
    const float* phit     = (const float*)d_in[4];
    const float* logt     = (const float*)d_in[5];
    float* out = (float*)d_out;

    char* ws = (char*)d_ws;
    short* zbf   = (short*)(ws + ZB_B);
    float* sp    = (float*)(ws + SP_B);
    float* mu    = (float*)(ws + MU_B);
    short* covb  = (short*)(ws + COV_B);
    float* U     = (float*)(ws + U_B);
    float* cross = (float*)(ws + CROSS_B);
    float* gram  = (float*)(ws + GRAM_B);
    float* w     = (float*)(ws + W_B);

    k_zgemm<<<dim3(50, 12), 256, 0, stream>>>(teacherT, phit, zbf, DT, 0);
    k_zgemm<<<dim3(50, 4), 256, 0, stream>>>(student, phis, zbf, DS, 12);
    k_means<<<dim3(16, 16), 256, 0, stream>>>(zbf, mu);
    k_covp<<<dim3(KS_COV, 16), 256, 0, stream>>>(zbf, sp);
    k_covfin<<<dim3(16, 8), 256, 0, stream>>>(sp, mu, covb);
    k_eigen<<<16, 512, 0, stream>>>(covb, U);
    k_gram<<<114, 256, 0, stream>>>(U, cross, gram);
    k_weights<<<1, 128, 0, stream>>>(gram, cross, mu, logt, w, out + 78976512);

    const size_t NL_T = (size_t)MROWS * DT;           // 4,841,472
    const size_t NL_A = (size_t)32 * 12 * 197 * 197;  // 14,902,656
    k_mix<<<2048, 256, 0, stream>>>(teacherT, w, out, (int)(NL_T / 4), NL_T);
    k_mix<<<4096, 256, 0, stream>>>(teacherA, w, out + 19365888, (int)(NL_A / 4), NL_A);
}

// Round 5
// 619.250 us; speedup vs baseline: 4.1967x; 1.1268x over previous
//
#include <hip/hip_runtime.h>
#include <hip/hip_bf16.h>
#include <stdint.h>

typedef __attribute__((ext_vector_type(8))) short s16x8;
typedef __attribute__((ext_vector_type(4))) short s16x4;
typedef __attribute__((ext_vector_type(4))) float f32x4;

#define L_T 12
#define P_S 4
#define NMAT 16
#define MROWS 6304
#define PD 128
#define DT 768
#define DS 384
#define KSUB 16
#define NIT 32

// ---- workspace byte offsets (16B aligned) ----
// S   : 16*16384 f32 = 1,048,576 B   (zeroed each call)
// cs  : 16*128 f32   = 8,192 B       (zeroed each call)
// mu  : 16*128 f32
// U   : 16*16*128 f32 = 131,072 B
// cross 144 f32, gram 48 f32, w 48 f32
#define S_B     0
#define CS_B    1048576
#define MU_B    1056768
#define U_B     1064960
#define CROSS_B 1196032
#define GRAM_B  1196608
#define W_B     1196800
#define NZERO   264192   // (16*16384 + 16*128) floats

__device__ __forceinline__ short f2bf(float f) {
    __hip_bfloat16 h = __float2bfloat16(f);
    return *reinterpret_cast<short*>(&h);
}
__device__ __forceinline__ float bf2f(short s) {
    union { uint32_t u; float f; } c;
    c.u = ((uint32_t)(uint16_t)s) << 16;
    return c.f;
}

// ------------------------------------------------------------------
// K0: zero S and colsum accumulators. grid 1032, block 256.
// ------------------------------------------------------------------
__global__ __launch_bounds__(256) void k_zero(float* __restrict__ p, int n) {
    int i = blockIdx.x * 256 + threadIdx.x;
    if (i < n) p[i] = 0.f;
}

// ------------------------------------------------------------------
// K1: fused projection + covariance partials.
// z-tile = tokens @ phi^T (bf16 MFMA), kept in LDS; then S += z^T z and
// colsum += sum_m z via fp32 atomics. grid (50,16), block 256.
// mats 0..11: teacher (D=768), 12..15: student (D=384).
// ------------------------------------------------------------------
__global__ __launch_bounds__(256) void k_zcov(const float* __restrict__ Tt,
                                              const float* __restrict__ St,
                                              const float* __restrict__ phit,
                                              const float* __restrict__ phis,
                                              float* __restrict__ S_g,
                                              float* __restrict__ cs_g) {
    __shared__ short As[128][40];
    __shared__ short Ws[128][40];
    __shared__ short Zs[128][136];
    int mat = blockIdx.y;
    const float* A; const float* W; int D;
    if (mat < L_T) { A = Tt + (size_t)mat * MROWS * DT; W = phit; D = DT; }
    else           { A = St + (size_t)(mat - L_T) * MROWS * DS; W = phis; D = DS; }
    int m0 = blockIdx.x * 128;
    int tid = threadIdx.x;
    int wid = tid >> 6, lane = tid & 63;
    int rw = lane & 15, kb = lane >> 4;
    f32x4 acc[2][8];
#pragma unroll
    for (int r = 0; r < 2; r++)
#pragma unroll
        for (int c = 0; c < 8; c++) acc[r][c] = (f32x4){0.f, 0.f, 0.f, 0.f};

    for (int d0 = 0; d0 < D; d0 += 32) {
        __syncthreads();
#pragma unroll
        for (int ii = 0; ii < 4; ii++) {
            int f = tid + 256 * ii;
            int row = f >> 3, c4 = (f & 7) << 2;
            int m = m0 + row;
            float4 v = make_float4(0.f, 0.f, 0.f, 0.f);
            if (m < MROWS) v = *(const float4*)(A + (size_t)m * D + d0 + c4);
            s16x4 h;
            h[0] = f2bf(v.x); h[1] = f2bf(v.y); h[2] = f2bf(v.z); h[3] = f2bf(v.w);
            *(s16x4*)&As[row][c4] = h;
        }
#pragma unroll
        for (int ii = 0; ii < 4; ii++) {
            int f = tid + 256 * ii;
            int row = f >> 3, c4 = (f & 7) << 2;
            float4 v = *(const float4*)(W + (size_t)row * D + d0 + c4);
            s16x4 h;
            h[0] = f2bf(v.x); h[1] = f2bf(v.y); h[2] = f2bf(v.z); h[3] = f2bf(v.w);
            *(s16x4*)&Ws[row][c4] = h;
        }
        __syncthreads();
        s16x8 ah[2];
#pragma unroll
        for (int r = 0; r < 2; r++)
            ah[r] = *(s16x8*)&As[32 * wid + 16 * r + rw][kb * 8];
#pragma unroll
        for (int c = 0; c < 8; c++) {
            s16x8 wv = *(s16x8*)&Ws[16 * c + rw][kb * 8];
#pragma unroll
            for (int r = 0; r < 2; r++)
                acc[r][c] = __builtin_amdgcn_mfma_f32_16x16x32_bf16(ah[r], wv, acc[r][c], 0, 0, 0);
        }
    }
    // z-tile (bf16) -> LDS, layout Zs[q][m_local]
    __syncthreads();
#pragma unroll
    for (int c = 0; c < 8; c++) {
        int q = 16 * c + rw;
#pragma unroll
        for (int r = 0; r < 2; r++) {
            s16x4 o;
            o[0] = f2bf(acc[r][c][0]); o[1] = f2bf(acc[r][c][1]);
            o[2] = f2bf(acc[r][c][2]); o[3] = f2bf(acc[r][c][3]);
            *(s16x4*)&Zs[q][32 * wid + 16 * r + 4 * kb] = o;
        }
    }
    __syncthreads();
    // colsum partial (rows beyond MROWS are zero -> harmless)
    if (tid < 128) {
        float s = 0.f;
#pragma unroll
        for (int mm = 0; mm < 128; mm += 8) {
            s16x8 v = *(s16x8*)&Zs[tid][mm];
#pragma unroll
            for (int u = 0; u < 8; u++) s += bf2f(v[u]);
        }
        atomicAdd(cs_g + mat * PD + tid, s);
    }
    // S partial: S += z^T z  (128x128, K=128)
    f32x4 a2[2][8];
#pragma unroll
    for (int r = 0; r < 2; r++)
#pragma unroll
        for (int cc = 0; cc < 8; cc++) a2[r][cc] = (f32x4){0.f, 0.f, 0.f, 0.f};
#pragma unroll
    for (int kc = 0; kc < 4; kc++) {
        s16x8 fr[8];
#pragma unroll
        for (int t = 0; t < 8; t++) fr[t] = *(s16x8*)&Zs[16 * t + rw][kc * 32 + kb * 8];
#pragma unroll
        for (int r = 0; r < 2; r++)
#pragma unroll
            for (int cc = 0; cc < 8; cc++)
                a2[r][cc] = __builtin_amdgcn_mfma_f32_16x16x32_bf16(
                    fr[2 * wid + r], fr[cc], a2[r][cc], 0, 0, 0);
    }
    float* sb = S_g + (size_t)mat * 16384;
#pragma unroll
    for (int r = 0; r < 2; r++)
#pragma unroll
        for (int cc = 0; cc < 8; cc++)
#pragma unroll
            for (int rr = 0; rr < 4; rr++) {
                int row = (2 * wid + r) * 16 + 4 * kb + rr;
                int col = 16 * cc + rw;
                atomicAdd(sb + row * 128 + col, a2[r][cc][rr]);
            }
}

// ------------------------------------------------------------------
// K2: top-16 invariant subspace. grid 16, block 512.
// Prologue: cov = S/M - mu mu^T -> bf16 LDS; writes mu to global.
// Loop: matvec (bf16 MFMA); CholQR every 2 steps; final CholQR fp32.
// Non-orth iterations: 1 sync, Q written straight from registers
// (double-buffered Qbf kills the read/write race).
// ------------------------------------------------------------------
__global__ __launch_bounds__(512) void k_eigen(const float* __restrict__ S_g,
                                               const float* __restrict__ cs_g,
                                               float* __restrict__ mu_g,
                                               float* __restrict__ U) {
    __shared__ short Abf[128][136];
    __shared__ short Qbf[2][16][136];
    __shared__ float Yt[16][132];
    __shared__ float G[16][17];
    __shared__ float Lc[16][17];
    __shared__ float mu_sh[128];
    int mat = blockIdx.x, tid = threadIdx.x;
    int wid = tid >> 6, lane = tid & 63;
    int rw = lane & 15, kb = lane >> 4;
    if (tid < 128) {
        float m_ = cs_g[mat * PD + tid] * (1.0f / MROWS);
        mu_sh[tid] = m_;
        mu_g[mat * PD + tid] = m_;
    }
    __syncthreads();
    {   // cov finalize -> bf16 LDS
        const float* sb = S_g + (size_t)mat * 16384;
        int i = tid >> 2, j0 = (tid & 3) << 5;
        float mi = mu_sh[i];
#pragma unroll
        for (int jj = 0; jj < 32; jj += 4) {
            float4 v = *(const float4*)(sb + i * 128 + j0 + jj);
            s16x4 o;
            o[0] = f2bf(v.x * (1.0f / MROWS) - mi * mu_sh[j0 + jj]);
            o[1] = f2bf(v.y * (1.0f / MROWS) - mi * mu_sh[j0 + jj + 1]);
            o[2] = f2bf(v.z * (1.0f / MROWS) - mi * mu_sh[j0 + jj + 2]);
            o[3] = f2bf(v.w * (1.0f / MROWS) - mi * mu_sh[j0 + jj + 3]);
            *(s16x4*)&Abf[i][j0 + jj] = o;
        }
    }
    {   // init Q[0] (deterministic hash)
#pragma unroll
        for (int u = 0; u < 4; u++) {
            int e = tid * 4 + u;
            int j = e >> 7, m = e & 127;
            uint32_t x = (uint32_t)e ^ (0x9E3779B9u * (uint32_t)(mat + 1));
            x ^= x >> 16; x *= 0x7feb352du; x ^= x >> 15; x *= 0x846ca68bu; x ^= x >> 16;
            float v = (float)(int)x * 4.6566129e-10f;
            Qbf[0][j][m] = f2bf(v);
        }
    }
    int cur = 0;
    for (int it = 0; it < NIT; it++) {
        __syncthreads();                     // Abf/Qbf[cur] ready
        f32x4 acc = (f32x4){0.f, 0.f, 0.f, 0.f};
#pragma unroll
        for (int kc = 0; kc < 4; kc++) {
            s16x8 a = *(s16x8*)&Abf[16 * wid + rw][kc * 32 + kb * 8];
            s16x8 b = *(s16x8*)&Qbf[cur][rw][kc * 32 + kb * 8];
            acc = __builtin_amdgcn_mfma_f32_16x16x32_bf16(a, b, acc, 0, 0, 0);
        }
        bool fin = (it == NIT - 1);
        if (!((it & 1) || fin)) {
            // plain power step: Q[cur^1] <- bf16(A Q[cur]) straight from regs
            s16x4 sv;
            sv[0] = f2bf(acc[0]); sv[1] = f2bf(acc[1]);
            sv[2] = f2bf(acc[2]); sv[3] = f2bf(acc[3]);
            *(s16x4*)&Qbf[cur ^ 1][rw][16 * wid + 4 * kb] = sv;
            cur ^= 1;
        } else {
            *(f32x4*)&Yt[rw][16 * wid + 4 * kb] = acc;
            __syncthreads();                 // Yt ready
            if (tid < 256) {                 // fp32 Gram
                int i = tid >> 4, j = tid & 15;
                float s = 0.f;
                for (int mm = 0; mm < 128; mm += 4) {
                    float4 a = *(float4*)&Yt[i][mm];
                    float4 b = *(float4*)&Yt[j][mm];
                    s += a.x * b.x + a.y * b.y + a.z * b.z + a.w * b.w;
                }
                G[i][j] = s;
            }
            __syncthreads();                 // G ready
            if (tid < 16) {                  // wave-synchronous Cholesky + ridge
                float g[16], Lr[16];
#pragma unroll
                for (int j = 0; j < 16; j++) g[j] = G[tid][j];
                float tr = g[tid];
#pragma unroll
                for (int off = 8; off > 0; off >>= 1) tr += __shfl_xor(tr, off);
                g[tid] += (fin ? 1e-6f : 0.03f) * (tr * (1.0f / 16.0f));
#pragma unroll
                for (int j = 0; j < 16; j++) {
                    float s = g[j];
#pragma unroll
                    for (int k = 0; k < j; k++) s -= Lr[k] * __shfl(Lr[k], j);
                    float dj = __shfl(s, j);
                    float d = sqrtf(fmaxf(dj, 1e-20f));
                    Lr[j] = (tid == j) ? d : ((tid > j) ? s / d : 0.f);
                }
#pragma unroll
                for (int j = 0; j < 16; j++) Lc[tid][j] = Lr[j];
            }
            __syncthreads();                 // Lc ready
            if (tid < 128) {                 // trisolve per column m
                int m = tid;
                float q[16];
#pragma unroll
                for (int j = 0; j < 16; j++) {
                    float s = Yt[j][m];
#pragma unroll
                    for (int k = 0; k < j; k++) s -= Lc[j][k] * q[k];
                    q[j] = s / Lc[j][j];
                }
                if (fin) {
                    float* ub = U + (size_t)mat * KSUB * PD;
#pragma unroll
                    for (int j = 0; j < 16; j++) ub[j * PD + m] = q[j];
                } else {
#pragma unroll
                    for (int j = 0; j < 16; j++) Qbf[cur ^ 1][j][m] = f2bf(q[j]);
                }
            }
            cur ^= 1;
        }
    }
}

// ------------------------------------------------------------------
// K3: pairwise ||U_a^T U_b||_F^2. grid 114, block 256.
// ------------------------------------------------------------------
__global__ __launch_bounds__(256) void k_gram(const float* __restrict__ U,
                                              float* __restrict__ cross,
                                              float* __restrict__ gram) {
    __shared__ float red[256];
    int bid = blockIdx.x;
    int ma, mb; bool isCross;
    if (bid < 66) {
        int a = 0, rem = bid;
        while (rem >= 11 - a) { rem -= 11 - a; a++; }
        ma = a; mb = a + 1 + rem; isCross = true;
    } else {
        int idx = bid - 66;
        ma = 12 + idx / 12; mb = idx % 12; isCross = false;
    }
    int tid = threadIdx.x;
    int i = tid >> 4, j = tid & 15;
    const float* ua = U + ((size_t)ma * KSUB + i) * PD;
    const float* ub = U + ((size_t)mb * KSUB + j) * PD;
    float s = 0.f;
    for (int m = 0; m < PD; m += 4) {
        float4 x = *(const float4*)(ua + m);
        float4 y = *(const float4*)(ub + m);
        s += x.x * y.x + x.y * y.y + x.z * y.z + x.w * y.w;
    }
    red[tid] = s * s;
    __syncthreads();
    for (int st = 128; st > 0; st >>= 1) {
        if (tid < st) red[tid] += red[tid + st];
        __syncthreads();
    }
    if (tid == 0) {
        if (isCross) { cross[ma * L_T + mb] = red[0]; cross[mb * L_T + ma] = red[0]; }
        else gram[(ma - 12) * L_T + mb] = red[0];
    }
}

// ------------------------------------------------------------------
// K4: softmax weights + reg_loss. 1 block, 128 threads.
// ------------------------------------------------------------------
__global__ __launch_bounds__(128) void k_weights(const float* __restrict__ gram,
                                                 const float* __restrict__ cross,
                                                 const float* __restrict__ mu,
                                                 const float* __restrict__ logt,
                                                 float* __restrict__ w,
                                                 float* __restrict__ loss_out) {
    __shared__ float wsm[P_S][L_T];
    __shared__ float red[128];
    int tid = threadIdx.x;
    if (tid < P_S) {
        float tau = log1pf(expf(logt[tid]));
        float x[L_T];
        float mx = -1e30f;
#pragma unroll
        for (int l = 0; l < L_T; l++) {
            float d = 1.0f - gram[tid * L_T + l] * (1.0f / 16.0f);
            x[l] = -d / tau;
            mx = fmaxf(mx, x[l]);
        }
        float ssum = 0.f;
#pragma unroll
        for (int l = 0; l < L_T; l++) { x[l] = expf(x[l] - mx); ssum += x[l]; }
        float inv = 1.0f / ssum;
#pragma unroll
        for (int l = 0; l < L_T; l++) { float wv = x[l] * inv; wsm[tid][l] = wv; w[tid * L_T + l] = wv; }
    }
    __syncthreads();
    float racc = 0.f;
    {
        int q = tid;
#pragma unroll
        for (int p = 0; p < P_S; p++) {
            float zm = 0.f;
#pragma unroll
            for (int l = 0; l < L_T; l++) zm += wsm[p][l] * mu[l * PD + q];
            float d = zm - mu[(12 + p) * PD + q];
            racc += d * d;
        }
    }
    red[tid] = racc;
    __syncthreads();
    for (int st = 64; st > 0; st >>= 1) {
        if (tid < st) red[tid] += red[tid + st];
        __syncthreads();
    }
    if (tid == 0) {
        float recon = red[0] * (1.0f / PD);
        float orth = 0.f;
        for (int p = 0; p < P_S; p++)
            for (int a = 0; a < L_T; a++)
                for (int b = 0; b < L_T; b++)
                    if (a != b) orth += wsm[p][a] * wsm[p][b] * cross[a * L_T + b];
        orth *= 0.5f;
        loss_out[0] = 0.01f * orth / P_S + 0.01f * recon / P_S;
    }
}

// ------------------------------------------------------------------
// K5/K6: out[p][i] = sum_l w[p][l] * in[l][i], float4 grid-stride.
// ------------------------------------------------------------------
__global__ __launch_bounds__(256) void k_mix(const float* __restrict__ in,
                                             const float* __restrict__ w,
                                             float* __restrict__ out,
                                             int nv, size_t nl) {
    float wr[P_S][L_T];
#pragma unroll
    for (int p = 0; p < P_S; p++)
#pragma unroll
        for (int l = 0; l < L_T; l++) wr[p][l] = w[p * L_T + l];
    int stride = gridDim.x * blockDim.x;
    for (int v = blockIdx.x * blockDim.x + threadIdx.x; v < nv; v += stride) {
        size_t off = (size_t)v * 4;
        float4 o[P_S];
#pragma unroll
        for (int p = 0; p < P_S; p++) o[p] = make_float4(0.f, 0.f, 0.f, 0.f);
#pragma unroll
        for (int l = 0; l < L_T; l++) {
            float4 x = *(const float4*)(in + (size_t)l * nl + off);
#pragma unroll
            for (int p = 0; p < P_S; p++) {
                o[p].x += wr[p][l] * x.x; o[p].y += wr[p][l] * x.y;
                o[p].z += wr[p][l] * x.z; o[p].w += wr[p][l] * x.w;
            }
        }
#pragma unroll
        for (int p = 0; p < P_S; p++)
            *(float4*)(out + (size_t)p * nl + off) = o[p];
    }
}

extern "C" void kernel_launch(void* const* d_in, const int* in_sizes, int n_in,
                              void* d_out, int out_size, void* d_ws, size_t ws_size,
                              hipStream_t stream) {
    const float* student  = (const float*)d_in[0];
    const float* teacherT = (const float*)d_in[1];
    const float* teacherA = (const float*)d_in[2];
    const float* phis     = (const float*)d_in[3];
    const float* phit     = (const float*)d_in[4];
    const float* logt     = (const float*)d_in[5];
    float* out = (float*)d_out;

    char* ws = (char*)d_ws;
    float* S_g   = (float*)(ws + S_B);
    float* cs_g  = (float*)(ws + CS_B);
    float* mu    = (float*)(ws + MU_B);
    float* U     = (float*)(ws + U_B);
    float* cross = (float*)(ws + CROSS_B);
    float* gram  = (float*)(ws + GRAM_B);
    float* w     = (float*)(ws + W_B);

    k_zero<<<(NZERO + 255) / 256, 256, 0, stream>>>(S_g, NZERO);
    k_zcov<<<dim3(50, 16), 256, 0, stream>>>(teacherT, student, phit, phis, S_g, cs_g);
    k_eigen<<<16, 512, 0, stream>>>(S_g, cs_g, mu, U);
    k_gram<<<114, 256, 0, stream>>>(U, cross, gram);
    k_weights<<<1, 128, 0, stream>>>(gram, cross, mu, logt, w, out + 78976512);

    const size_t NL_T = (size_t)MROWS * DT;           // 4,841,472
    const size_t NL_A = (size_t)32 * 12 * 197 * 197;  // 14,902,656
    k_mix<<<2048, 256, 0, stream>>>(teacherT, w, out, (int)(NL_T / 4), NL_T);
    k_mix<<<4096, 256, 0, stream>>>(teacherA, w, out + 19365888, (int)(NL_A / 4), NL_A);
}

// Round 6
// 569.691 us; speedup vs baseline: 4.5618x; 1.0870x over previous
//
#include <hip/hip_runtime.h>
#include <hip/hip_bf16.h>
#include <stdint.h>

typedef __attribute__((ext_vector_type(8))) short s16x8;
typedef __attribute__((ext_vector_type(4))) short s16x4;
typedef __attribute__((ext_vector_type(4))) float f32x4;

#define L_T 12
#define P_S 4
#define NMAT 16
#define MROWS 6304
#define PD 128
#define DT 768
#define DS 384
#define KSUB 16
#define NIT 24

// ---- workspace byte offsets (16B aligned) ----
#define S_B     0
#define CS_B    1048576
#define MU_B    1056768
#define U_B     1064960
#define CROSS_B 1196032
#define GRAM_B  1196672
#define W_B     1196928
#define WBT_B   1197184
#define WBS_B   1393792
#define NZERO   264192   // (16*16384 + 16*128) floats

__device__ __forceinline__ short f2bf(float f) {
    __hip_bfloat16 h = __float2bfloat16(f);
    return *reinterpret_cast<short*>(&h);
}
__device__ __forceinline__ float bf2f(short s) {
    union { uint32_t u; float f; } c;
    c.u = ((uint32_t)(uint16_t)s) << 16;
    return c.f;
}

// ------------------------------------------------------------------
// K0: zero S and colsum accumulators.
// ------------------------------------------------------------------
__global__ __launch_bounds__(256) void k_zero(float* __restrict__ p, int n) {
    int i = blockIdx.x * 256 + threadIdx.x;
    if (i < n) p[i] = 0.f;
}

// ------------------------------------------------------------------
// K0b: convert phi_t (98304 f32) and phi_s (49152 f32) to bf16 once.
// grid 144, block 256.
// ------------------------------------------------------------------
__global__ __launch_bounds__(256) void k_wcvt(const float* __restrict__ phit,
                                              const float* __restrict__ phis,
                                              short* __restrict__ wbt,
                                              short* __restrict__ wbs) {
    int e = (blockIdx.x * 256 + threadIdx.x) * 4;
    const float* src; short* dst; int off;
    if (e < PD * DT) { src = phit; dst = wbt; off = e; }
    else             { src = phis; dst = wbs; off = e - PD * DT; }
    float4 v = *(const float4*)(src + off);
    s16x4 h;
    h[0] = f2bf(v.x); h[1] = f2bf(v.y); h[2] = f2bf(v.z); h[3] = f2bf(v.w);
    *(s16x4*)(dst + off) = h;
}

// ------------------------------------------------------------------
// K1: fused projection + covariance partials. grid (50,16), block 256.
// ------------------------------------------------------------------
__global__ __launch_bounds__(256) void k_zcov(const float* __restrict__ Tt,
                                              const float* __restrict__ St,
                                              const short* __restrict__ wbt,
                                              const short* __restrict__ wbs,
                                              float* __restrict__ S_g,
                                              float* __restrict__ cs_g) {
    __shared__ short As[128][40];
    __shared__ short Ws[128][40];
    __shared__ short Zs[128][136];
    int mat = blockIdx.y;
    const float* A; const short* Wb; int D;
    if (mat < L_T) { A = Tt + (size_t)mat * MROWS * DT; Wb = wbt; D = DT; }
    else           { A = St + (size_t)(mat - L_T) * MROWS * DS; Wb = wbs; D = DS; }
    int m0 = blockIdx.x * 128;
    int tid = threadIdx.x;
    int wid = tid >> 6, lane = tid & 63;
    int rw = lane & 15, kb = lane >> 4;
    f32x4 acc[2][8];
#pragma unroll
    for (int r = 0; r < 2; r++)
#pragma unroll
        for (int c = 0; c < 8; c++) acc[r][c] = (f32x4){0.f, 0.f, 0.f, 0.f};

    for (int d0 = 0; d0 < D; d0 += 32) {
        __syncthreads();
#pragma unroll
        for (int ii = 0; ii < 4; ii++) {
            int f = tid + 256 * ii;
            int row = f >> 3, c4 = (f & 7) << 2;
            int m = m0 + row;
            float4 v = make_float4(0.f, 0.f, 0.f, 0.f);
            if (m < MROWS) v = *(const float4*)(A + (size_t)m * D + d0 + c4);
            s16x4 h;
            h[0] = f2bf(v.x); h[1] = f2bf(v.y); h[2] = f2bf(v.z); h[3] = f2bf(v.w);
            *(s16x4*)&As[row][c4] = h;
        }
        // W already bf16 in global: 128 rows x 32 cols, 16B copies
#pragma unroll
        for (int ii = 0; ii < 2; ii++) {
            int f = tid + 256 * ii;
            int row = f >> 2, c8 = (f & 3) << 3;
            *(s16x8*)&Ws[row][c8] = *(const s16x8*)(Wb + (size_t)row * D + d0 + c8);
        }
        __syncthreads();
        s16x8 ah[2];
#pragma unroll
        for (int r = 0; r < 2; r++)
            ah[r] = *(s16x8*)&As[32 * wid + 16 * r + rw][kb * 8];
#pragma unroll
        for (int c = 0; c < 8; c++) {
            s16x8 wv = *(s16x8*)&Ws[16 * c + rw][kb * 8];
#pragma unroll
            for (int r = 0; r < 2; r++)
                acc[r][c] = __builtin_amdgcn_mfma_f32_16x16x32_bf16(ah[r], wv, acc[r][c], 0, 0, 0);
        }
    }
    __syncthreads();
#pragma unroll
    for (int c = 0; c < 8; c++) {
        int q = 16 * c + rw;
#pragma unroll
        for (int r = 0; r < 2; r++) {
            s16x4 o;
            o[0] = f2bf(acc[r][c][0]); o[1] = f2bf(acc[r][c][1]);
            o[2] = f2bf(acc[r][c][2]); o[3] = f2bf(acc[r][c][3]);
            *(s16x4*)&Zs[q][32 * wid + 16 * r + 4 * kb] = o;
        }
    }
    __syncthreads();
    if (tid < 128) {
        float s = 0.f;
#pragma unroll
        for (int mm = 0; mm < 128; mm += 8) {
            s16x8 v = *(s16x8*)&Zs[tid][mm];
#pragma unroll
            for (int u = 0; u < 8; u++) s += bf2f(v[u]);
        }
        atomicAdd(cs_g + mat * PD + tid, s);
    }
    f32x4 a2[2][8];
#pragma unroll
    for (int r = 0; r < 2; r++)
#pragma unroll
        for (int cc = 0; cc < 8; cc++) a2[r][cc] = (f32x4){0.f, 0.f, 0.f, 0.f};
#pragma unroll
    for (int kc = 0; kc < 4; kc++) {
        s16x8 fr[8];
#pragma unroll
        for (int t = 0; t < 8; t++) fr[t] = *(s16x8*)&Zs[16 * t + rw][kc * 32 + kb * 8];
#pragma unroll
        for (int r = 0; r < 2; r++)
#pragma unroll
            for (int cc = 0; cc < 8; cc++)
                a2[r][cc] = __builtin_amdgcn_mfma_f32_16x16x32_bf16(
                    fr[2 * wid + r], fr[cc], a2[r][cc], 0, 0, 0);
    }
    float* sb = S_g + (size_t)mat * 16384;
#pragma unroll
    for (int r = 0; r < 2; r++)
#pragma unroll
        for (int cc = 0; cc < 8; cc++)
#pragma unroll
            for (int rr = 0; rr < 4; rr++) {
                int row = (2 * wid + r) * 16 + 4 * kb + rr;
                int col = 16 * cc + rw;
                atomicAdd(sb + row * 128 + col, a2[r][cc][rr]);
            }
}

// ------------------------------------------------------------------
// K2: top-16 invariant subspace. grid 16, block 512.
// ------------------------------------------------------------------
__global__ __launch_bounds__(512) void k_eigen(const float* __restrict__ S_g,
                                               const float* __restrict__ cs_g,
                                               float* __restrict__ mu_g,
                                               float* __restrict__ U) {
    __shared__ short Abf[128][136];
    __shared__ short Qbf[2][16][136];
    __shared__ float Yt[16][132];
    __shared__ float G[16][17];
    __shared__ float Lc[16][17];
    __shared__ float mu_sh[128];
    int mat = blockIdx.x, tid = threadIdx.x;
    int wid = tid >> 6, lane = tid & 63;
    int rw = lane & 15, kb = lane >> 4;
    if (tid < 128) {
        float m_ = cs_g[mat * PD + tid] * (1.0f / MROWS);
        mu_sh[tid] = m_;
        mu_g[mat * PD + tid] = m_;
    }
    __syncthreads();
    {   // cov finalize -> bf16 LDS
        const float* sb = S_g + (size_t)mat * 16384;
        int i = tid >> 2, j0 = (tid & 3) << 5;
        float mi = mu_sh[i];
#pragma unroll
        for (int jj = 0; jj < 32; jj += 4) {
            float4 v = *(const float4*)(sb + i * 128 + j0 + jj);
            s16x4 o;
            o[0] = f2bf(v.x * (1.0f / MROWS) - mi * mu_sh[j0 + jj]);
            o[1] = f2bf(v.y * (1.0f / MROWS) - mi * mu_sh[j0 + jj + 1]);
            o[2] = f2bf(v.z * (1.0f / MROWS) - mi * mu_sh[j0 + jj + 2]);
            o[3] = f2bf(v.w * (1.0f / MROWS) - mi * mu_sh[j0 + jj + 3]);
            *(s16x4*)&Abf[i][j0 + jj] = o;
        }
    }
    {   // init Q[0] (deterministic hash)
#pragma unroll
        for (int u = 0; u < 4; u++) {
            int e = tid * 4 + u;
            int j = e >> 7, m = e & 127;
            uint32_t x = (uint32_t)e ^ (0x9E3779B9u * (uint32_t)(mat + 1));
            x ^= x >> 16; x *= 0x7feb352du; x ^= x >> 15; x *= 0x846ca68bu; x ^= x >> 16;
            float v = (float)(int)x * 4.6566129e-10f;
            Qbf[0][j][m] = f2bf(v);
        }
    }
    int cur = 0;
    for (int it = 0; it < NIT; it++) {
        __syncthreads();
        f32x4 acc = (f32x4){0.f, 0.f, 0.f, 0.f};
#pragma unroll
        for (int kc = 0; kc < 4; kc++) {
            s16x8 a = *(s16x8*)&Abf[16 * wid + rw][kc * 32 + kb * 8];
            s16x8 b = *(s16x8*)&Qbf[cur][rw][kc * 32 + kb * 8];
            acc = __builtin_amdgcn_mfma_f32_16x16x32_bf16(a, b, acc, 0, 0, 0);
        }
        bool fin = (it == NIT - 1);
        if (!((it & 1) || fin)) {
            s16x4 sv;
            sv[0] = f2bf(acc[0]); sv[1] = f2bf(acc[1]);
            sv[2] = f2bf(acc[2]); sv[3] = f2bf(acc[3]);
            *(s16x4*)&Qbf[cur ^ 1][rw][16 * wid + 4 * kb] = sv;
            cur ^= 1;
        } else {
            *(f32x4*)&Yt[rw][16 * wid + 4 * kb] = acc;
            __syncthreads();
            if (tid < 256) {
                int i = tid >> 4, j = tid & 15;
                float s = 0.f;
                for (int mm = 0; mm < 128; mm += 4) {
                    float4 a = *(float4*)&Yt[i][mm];
                    float4 b = *(float4*)&Yt[j][mm];
                    s += a.x * b.x + a.y * b.y + a.z * b.z + a.w * b.w;
                }
                G[i][j] = s;
            }
            __syncthreads();
            if (tid < 16) {
                float g[16], Lr[16];
#pragma unroll
                for (int j = 0; j < 16; j++) g[j] = G[tid][j];
                float tr = g[tid];
#pragma unroll
                for (int off = 8; off > 0; off >>= 1) tr += __shfl_xor(tr, off);
                g[tid] += (fin ? 1e-6f : 0.03f) * (tr * (1.0f / 16.0f));
#pragma unroll
                for (int j = 0; j < 16; j++) {
                    float s = g[j];
#pragma unroll
                    for (int k = 0; k < j; k++) s -= Lr[k] * __shfl(Lr[k], j);
                    float dj = __shfl(s, j);
                    float d = sqrtf(fmaxf(dj, 1e-20f));
                    Lr[j] = (tid == j) ? d : ((tid > j) ? s / d : 0.f);
                }
#pragma unroll
                for (int j = 0; j < 16; j++) Lc[tid][j] = Lr[j];
            }
            __syncthreads();
            if (tid < 128) {
                int m = tid;
                float q[16];
#pragma unroll
                for (int j = 0; j < 16; j++) {
                    float s = Yt[j][m];
#pragma unroll
                    for (int k = 0; k < j; k++) s -= Lc[j][k] * q[k];
                    q[j] = s / Lc[j][j];
                }
                if (fin) {
                    float* ub = U + (size_t)mat * KSUB * PD;
#pragma unroll
                    for (int j = 0; j < 16; j++) ub[j * PD + m] = q[j];
                } else {
#pragma unroll
                    for (int j = 0; j < 16; j++) Qbf[cur ^ 1][j][m] = f2bf(q[j]);
                }
            }
            cur ^= 1;
        }
    }
}

// ------------------------------------------------------------------
// K3: pairwise ||U_a^T U_b||_F^2. grid 114, block 256.
// ------------------------------------------------------------------
__global__ __launch_bounds__(256) void k_gram(const float* __restrict__ U,
                                              float* __restrict__ cross,
                                              float* __restrict__ gram) {
    __shared__ float red[256];
    int bid = blockIdx.x;
    int ma, mb; bool isCross;
    if (bid < 66) {
        int a = 0, rem = bid;
        while (rem >= 11 - a) { rem -= 11 - a; a++; }
        ma = a; mb = a + 1 + rem; isCross = true;
    } else {
        int idx = bid - 66;
        ma = 12 + idx / 12; mb = idx % 12; isCross = false;
    }
    int tid = threadIdx.x;
    int i = tid >> 4, j = tid & 15;
    const float* ua = U + ((size_t)ma * KSUB + i) * PD;
    const float* ub = U + ((size_t)mb * KSUB + j) * PD;
    float s = 0.f;
    for (int m = 0; m < PD; m += 4) {
        float4 x = *(const float4*)(ua + m);
        float4 y = *(const float4*)(ub + m);
        s += x.x * y.x + x.y * y.y + x.z * y.z + x.w * y.w;
    }
    red[tid] = s * s;
    __syncthreads();
    for (int st = 128; st > 0; st >>= 1) {
        if (tid < st) red[tid] += red[tid + st];
        __syncthreads();
    }
    if (tid == 0) {
        if (isCross) { cross[ma * L_T + mb] = red[0]; cross[mb * L_T + ma] = red[0]; }
        else gram[(ma - 12) * L_T + mb] = red[0];
    }
}

// ------------------------------------------------------------------
// K4: softmax weights + reg_loss. 1 block, 128 threads.
// ------------------------------------------------------------------
__global__ __launch_bounds__(128) void k_weights(const float* __restrict__ gram,
                                                 const float* __restrict__ cross,
                                                 const float* __restrict__ mu,
                                                 const float* __restrict__ logt,
                                                 float* __restrict__ w,
                                                 float* __restrict__ loss_out) {
    __shared__ float wsm[P_S][L_T];
    __shared__ float red[128];
    int tid = threadIdx.x;
    if (tid < P_S) {
        float tau = log1pf(expf(logt[tid]));
        float x[L_T];
        float mx = -1e30f;
#pragma unroll
        for (int l = 0; l < L_T; l++) {
            float d = 1.0f - gram[tid * L_T + l] * (1.0f / 16.0f);
            x[l] = -d / tau;
            mx = fmaxf(mx, x[l]);
        }
        float ssum = 0.f;
#pragma unroll
        for (int l = 0; l < L_T; l++) { x[l] = expf(x[l] - mx); ssum += x[l]; }
        float inv = 1.0f / ssum;
#pragma unroll
        for (int l = 0; l < L_T; l++) { float wv = x[l] * inv; wsm[tid][l] = wv; w[tid * L_T + l] = wv; }
    }
    __syncthreads();
    float racc = 0.f;
    {
        int q = tid;
#pragma unroll
        for (int p = 0; p < P_S; p++) {
            float zm = 0.f;
#pragma unroll
            for (int l = 0; l < L_T; l++) zm += wsm[p][l] * mu[l * PD + q];
            float d = zm - mu[(12 + p) * PD + q];
            racc += d * d;
        }
    }
    red[tid] = racc;
    __syncthreads();
    for (int st = 64; st > 0; st >>= 1) {
        if (tid < st) red[tid] += red[tid + st];
        __syncthreads();
    }
    if (tid == 0) {
        float recon = red[0] * (1.0f / PD);
        float orth = 0.f;
        for (int p = 0; p < P_S; p++)
            for (int a = 0; a < L_T; a++)
                for (int b = 0; b < L_T; b++)
                    if (a != b) orth += wsm[p][a] * wsm[p][b] * cross[a * L_T + b];
        orth *= 0.5f;
        loss_out[0] = 0.01f * orth / P_S + 0.01f * recon / P_S;
    }
}

// ------------------------------------------------------------------
// K5: fused mix (teachers + attns), nontemporal streaming.
// blocks [0,1280): teachers; [1280,5120): attns.
// ------------------------------------------------------------------
#define MIX_TB 1280
#define MIX_AB 3840
__global__ __launch_bounds__(256) void k_mix2(const float* __restrict__ Tt,
                                              const float* __restrict__ Ta,
                                              const float* __restrict__ w,
                                              float* __restrict__ outT,
                                              float* __restrict__ outA) {
    float wr[P_S][L_T];
#pragma unroll
    for (int p = 0; p < P_S; p++)
#pragma unroll
        for (int l = 0; l < L_T; l++) wr[p][l] = w[p * L_T + l];
    const float* in; float* out; size_t nl; int nv, v0, stride;
    if (blockIdx.x < MIX_TB) {
        in = Tt; out = outT; nl = (size_t)MROWS * DT;
        nv = (int)(nl / 4);
        v0 = blockIdx.x * 256 + threadIdx.x;
        stride = MIX_TB * 256;
    } else {
        in = Ta; out = outA; nl = (size_t)32 * 12 * 197 * 197;
        nv = (int)(nl / 4);
        v0 = (blockIdx.x - MIX_TB) * 256 + threadIdx.x;
        stride = MIX_AB * 256;
    }
    for (int v = v0; v < nv; v += stride) {
        f32x4 o[P_S];
#pragma unroll
        for (int p = 0; p < P_S; p++) o[p] = (f32x4){0.f, 0.f, 0.f, 0.f};
#pragma unroll
        for (int l = 0; l < L_T; l++) {
            f32x4 x = __builtin_nontemporal_load((const f32x4*)(in + (size_t)l * nl) + v);
#pragma unroll
            for (int p = 0; p < P_S; p++) {
                o[p][0] += wr[p][l] * x[0]; o[p][1] += wr[p][l] * x[1];
                o[p][2] += wr[p][l] * x[2]; o[p][3] += wr[p][l] * x[3];
            }
        }
#pragma unroll
        for (int p = 0; p < P_S; p++)
            __builtin_nontemporal_store(o[p], (f32x4*)(out + (size_t)p * nl) + v);
    }
}

extern "C" void kernel_launch(void* const* d_in, const int* in_sizes, int n_in,
                              void* d_out, int out_size, void* d_ws, size_t ws_size,
                              hipStream_t stream) {
    const float* student  = (const float*)d_in[0];
    const float* teacherT = (const float*)d_in[1];
    const float* teacherA = (const float*)d_in[2];
    const float* phis     = (const float*)d_in[3];
    const float* phit     = (const float*)d_in[4];
    const float* logt     = (const float*)d_in[5];
    float* out = (float*)d_out;

    char* ws = (char*)d_ws;
    float* S_g   = (float*)(ws + S_B);
    float* cs_g  = (float*)(ws + CS_B);
    float* mu    = (float*)(ws + MU_B);
    float* U     = (float*)(ws + U_B);
    float* cross = (float*)(ws + CROSS_B);
    float* gram  = (float*)(ws + GRAM_B);
    float* w     = (float*)(ws + W_B);
    short* wbt   = (short*)(ws + WBT_B);
    short* wbs   = (short*)(ws + WBS_B);

    k_zero<<<(NZERO + 255) / 256, 256, 0, stream>>>(S_g, NZERO);
    k_wcvt<<<144, 256, 0, stream>>>(phit, phis, wbt, wbs);
    k_zcov<<<dim3(50, 16), 256, 0, stream>>>(teacherT, student, wbt, wbs, S_g, cs_g);
    k_eigen<<<16, 512, 0, stream>>>(S_g, cs_g, mu, U);
    k_gram<<<114, 256, 0, stream>>>(U, cross, gram);
    k_weights<<<1, 128, 0, stream>>>(gram, cross, mu, logt, w, out + 78976512);
    k_mix2<<<MIX_TB + MIX_AB, 256, 0, stream>>>(teacherT, teacherA, w,
                                                out, out + 19365888);
}

// Round 7
// 514.245 us; speedup vs baseline: 5.0536x; 1.1078x over previous
//
#include <hip/hip_runtime.h>
#include <hip/hip_bf16.h>
#include <stdint.h>

typedef __attribute__((ext_vector_type(8))) short s16x8;
typedef __attribute__((ext_vector_type(4))) short s16x4;
typedef __attribute__((ext_vector_type(4))) float f32x4;

#define L_T 12
#define P_S 4
#define NMAT 16
#define MROWS 6304
#define PD 128
#define DT 768
#define DS 384
#define KSUB 16
#define NIT 20
#define NBLK 50

// ---- workspace byte offsets (16B aligned) ----
#define SPART_B 0            // 16*50*16384 f32 = 52,428,800
#define CS_B    52428800     // 2048 f32 (zeroed)
#define MU_B    52436992
#define COVB_B  52445184     // 16*16384 bf16
#define U_B     52969472
#define CROSS_B 53100544
#define GRAM_B  53101568
#define W_B     53102592
#define WBT_B   53103616
#define WBS_B   53300224

__device__ __forceinline__ short f2bf(float f) {
    __hip_bfloat16 h = __float2bfloat16(f);
    return *reinterpret_cast<short*>(&h);
}
__device__ __forceinline__ float bf2f(short s) {
    union { uint32_t u; float f; } c;
    c.u = ((uint32_t)(uint16_t)s) << 16;
    return c.f;
}

// ------------------------------------------------------------------
// K0: blocks [0,144): phi fp32->bf16; blocks [144,152): zero cs.
// ------------------------------------------------------------------
__global__ __launch_bounds__(256) void k_init(const float* __restrict__ phit,
                                              const float* __restrict__ phis,
                                              short* __restrict__ wbt,
                                              short* __restrict__ wbs,
                                              float* __restrict__ cs) {
    int b = blockIdx.x;
    if (b < 144) {
        int e = (b * 256 + threadIdx.x) * 4;
        const float* src; short* dst; int off;
        if (e < PD * DT) { src = phit; dst = wbt; off = e; }
        else             { src = phis; dst = wbs; off = e - PD * DT; }
        float4 v = *(const float4*)(src + off);
        s16x4 h;
        h[0] = f2bf(v.x); h[1] = f2bf(v.y); h[2] = f2bf(v.z); h[3] = f2bf(v.w);
        *(s16x4*)(dst + off) = h;
    } else {
        cs[(b - 144) * 256 + threadIdx.x] = 0.f;
    }
}

// ------------------------------------------------------------------
// K1: fused projection + covariance partials. grid (50,16), block 256.
// S-partials stored per-block (plain stores, no atomics).
// ------------------------------------------------------------------
__global__ __launch_bounds__(256) void k_zcov(const float* __restrict__ Tt,
                                              const float* __restrict__ St,
                                              const short* __restrict__ wbt,
                                              const short* __restrict__ wbs,
                                              float* __restrict__ spart,
                                              float* __restrict__ cs_g) {
    __shared__ short As[128][40];
    __shared__ short Ws[128][40];
    __shared__ short Zs[128][136];
    int mat = blockIdx.y;
    const float* A; const short* Wb; int D;
    if (mat < L_T) { A = Tt + (size_t)mat * MROWS * DT; Wb = wbt; D = DT; }
    else           { A = St + (size_t)(mat - L_T) * MROWS * DS; Wb = wbs; D = DS; }
    int m0 = blockIdx.x * 128;
    int tid = threadIdx.x;
    int wid = tid >> 6, lane = tid & 63;
    int rw = lane & 15, kb = lane >> 4;
    f32x4 acc[2][8];
#pragma unroll
    for (int r = 0; r < 2; r++)
#pragma unroll
        for (int c = 0; c < 8; c++) acc[r][c] = (f32x4){0.f, 0.f, 0.f, 0.f};

    for (int d0 = 0; d0 < D; d0 += 32) {
        __syncthreads();
#pragma unroll
        for (int ii = 0; ii < 4; ii++) {
            int f = tid + 256 * ii;
            int row = f >> 3, c4 = (f & 7) << 2;
            int m = m0 + row;
            float4 v = make_float4(0.f, 0.f, 0.f, 0.f);
            if (m < MROWS) v = *(const float4*)(A + (size_t)m * D + d0 + c4);
            s16x4 h;
            h[0] = f2bf(v.x); h[1] = f2bf(v.y); h[2] = f2bf(v.z); h[3] = f2bf(v.w);
            *(s16x4*)&As[row][c4] = h;
        }
#pragma unroll
        for (int ii = 0; ii < 2; ii++) {
            int f = tid + 256 * ii;
            int row = f >> 2, c8 = (f & 3) << 3;
            *(s16x8*)&Ws[row][c8] = *(const s16x8*)(Wb + (size_t)row * D + d0 + c8);
        }
        __syncthreads();
        s16x8 ah[2];
#pragma unroll
        for (int r = 0; r < 2; r++)
            ah[r] = *(s16x8*)&As[32 * wid + 16 * r + rw][kb * 8];
#pragma unroll
        for (int c = 0; c < 8; c++) {
            s16x8 wv = *(s16x8*)&Ws[16 * c + rw][kb * 8];
#pragma unroll
            for (int r = 0; r < 2; r++)
                acc[r][c] = __builtin_amdgcn_mfma_f32_16x16x32_bf16(ah[r], wv, acc[r][c], 0, 0, 0);
        }
    }
    __syncthreads();
#pragma unroll
    for (int c = 0; c < 8; c++) {
        int q = 16 * c + rw;
#pragma unroll
        for (int r = 0; r < 2; r++) {
            s16x4 o;
            o[0] = f2bf(acc[r][c][0]); o[1] = f2bf(acc[r][c][1]);
            o[2] = f2bf(acc[r][c][2]); o[3] = f2bf(acc[r][c][3]);
            *(s16x4*)&Zs[q][32 * wid + 16 * r + 4 * kb] = o;
        }
    }
    __syncthreads();
    if (tid < 128) {
        float s = 0.f;
#pragma unroll
        for (int mm = 0; mm < 128; mm += 8) {
            s16x8 v = *(s16x8*)&Zs[tid][mm];
#pragma unroll
            for (int u = 0; u < 8; u++) s += bf2f(v[u]);
        }
        atomicAdd(cs_g + mat * PD + tid, s);
    }
    f32x4 a2[2][8];
#pragma unroll
    for (int r = 0; r < 2; r++)
#pragma unroll
        for (int cc = 0; cc < 8; cc++) a2[r][cc] = (f32x4){0.f, 0.f, 0.f, 0.f};
#pragma unroll
    for (int kc = 0; kc < 4; kc++) {
        s16x8 fr[8];
#pragma unroll
        for (int t = 0; t < 8; t++) fr[t] = *(s16x8*)&Zs[16 * t + rw][kc * 32 + kb * 8];
#pragma unroll
        for (int r = 0; r < 2; r++)
#pragma unroll
            for (int cc = 0; cc < 8; cc++)
                a2[r][cc] = __builtin_amdgcn_mfma_f32_16x16x32_bf16(
                    fr[2 * wid + r], fr[cc], a2[r][cc], 0, 0, 0);
    }
    float* sb = spart + ((size_t)mat * NBLK + blockIdx.x) * 16384;
#pragma unroll
    for (int r = 0; r < 2; r++)
#pragma unroll
        for (int cc = 0; cc < 8; cc++)
#pragma unroll
            for (int rr = 0; rr < 4; rr++) {
                int row = (2 * wid + r) * 16 + 4 * kb + rr;
                int col = 16 * cc + rw;
                sb[row * 128 + col] = a2[r][cc][rr];
            }
}

// ------------------------------------------------------------------
// K2: reduce S-partials, finalize cov -> bf16, write mu.
// grid (8,16), block 256.
// ------------------------------------------------------------------
__global__ __launch_bounds__(256) void k_covred(const float* __restrict__ spart,
                                                const float* __restrict__ cs_g,
                                                float* __restrict__ mu_g,
                                                short* __restrict__ covb) {
    int mat = blockIdx.y, seg = blockIdx.x;
    int tid = threadIdx.x;
    int e0 = (seg * 256 + tid) * 8;
    float s[8];
#pragma unroll
    for (int u = 0; u < 8; u++) s[u] = 0.f;
    const float* base = spart + (size_t)mat * NBLK * 16384 + e0;
    for (int b = 0; b < NBLK; b++) {
        const float* p = base + (size_t)b * 16384;
        float4 u0 = *(const float4*)(p);
        float4 u1 = *(const float4*)(p + 4);
        s[0] += u0.x; s[1] += u0.y; s[2] += u0.z; s[3] += u0.w;
        s[4] += u1.x; s[5] += u1.y; s[6] += u1.z; s[7] += u1.w;
    }
    int i = e0 >> 7, j0 = e0 & 127;
    float mi = cs_g[mat * PD + i] * (1.0f / MROWS);
    s16x8 o;
#pragma unroll
    for (int u = 0; u < 8; u++) {
        float mj = cs_g[mat * PD + j0 + u] * (1.0f / MROWS);
        o[u] = f2bf(s[u] * (1.0f / MROWS) - mi * mj);
    }
    *(s16x8*)(covb + (size_t)mat * 16384 + e0) = o;
    if (seg == 0 && tid < 128)
        mu_g[mat * PD + tid] = cs_g[mat * PD + tid] * (1.0f / MROWS);
}

// ------------------------------------------------------------------
// K3: top-16 invariant subspace. grid 16, block 512.
// CholQR every 4 steps; A-fragments hoisted to registers;
// trisolve uses precomputed diagonal reciprocals (no fdiv chain).
// ------------------------------------------------------------------
__global__ __launch_bounds__(512) void k_eigen(const short* __restrict__ covb,
                                               float* __restrict__ U) {
    __shared__ short Abf[128][136];
    __shared__ short Qbf[2][16][136];
    __shared__ float Yt[16][132];
    __shared__ float G[16][17];
    __shared__ float Lc[16][17];
    __shared__ float rinvs[16];
    int mat = blockIdx.x, tid = threadIdx.x;
    int wid = tid >> 6, lane = tid & 63;
    int rw = lane & 15, kb = lane >> 4;
    {   // load A (bf16 copy)
        int row = tid >> 2, sg = (tid & 3) << 5;
        const short* src = covb + (size_t)mat * 16384 + row * 128 + sg;
#pragma unroll
        for (int k = 0; k < 4; k++)
            *(s16x8*)&Abf[row][sg + 8 * k] = *(const s16x8*)(src + 8 * k);
    }
    {   // init Q[0] (deterministic hash)
#pragma unroll
        for (int u = 0; u < 4; u++) {
            int e = tid * 4 + u;
            int j = e >> 7, m = e & 127;
            uint32_t x = (uint32_t)e ^ (0x9E3779B9u * (uint32_t)(mat + 1));
            x ^= x >> 16; x *= 0x7feb352du; x ^= x >> 15; x *= 0x846ca68bu; x ^= x >> 16;
            float v = (float)(int)x * 4.6566129e-10f;
            Qbf[0][j][m] = f2bf(v);
        }
    }
    __syncthreads();
    // hoist loop-invariant A fragments into registers
    s16x8 areg[4];
#pragma unroll
    for (int kc = 0; kc < 4; kc++)
        areg[kc] = *(s16x8*)&Abf[16 * wid + rw][kc * 32 + kb * 8];

    int cur = 0;
    for (int it = 0; it < NIT; it++) {
        __syncthreads();                     // Qbf[cur] ready
        f32x4 acc = (f32x4){0.f, 0.f, 0.f, 0.f};
#pragma unroll
        for (int kc = 0; kc < 4; kc++) {
            s16x8 b = *(s16x8*)&Qbf[cur][rw][kc * 32 + kb * 8];
            acc = __builtin_amdgcn_mfma_f32_16x16x32_bf16(areg[kc], b, acc, 0, 0, 0);
        }
        bool fin = (it == NIT - 1);
        bool orth = ((it & 3) == 3) || fin;
        if (!orth) {
            s16x4 sv;
            sv[0] = f2bf(acc[0]); sv[1] = f2bf(acc[1]);
            sv[2] = f2bf(acc[2]); sv[3] = f2bf(acc[3]);
            *(s16x4*)&Qbf[cur ^ 1][rw][16 * wid + 4 * kb] = sv;
            cur ^= 1;
        } else {
            *(f32x4*)&Yt[rw][16 * wid + 4 * kb] = acc;
            __syncthreads();
            if (tid < 256) {                 // fp32 Gram
                int i = tid >> 4, j = tid & 15;
                float s = 0.f;
                for (int mm = 0; mm < 128; mm += 4) {
                    float4 a = *(float4*)&Yt[i][mm];
                    float4 b = *(float4*)&Yt[j][mm];
                    s += a.x * b.x + a.y * b.y + a.z * b.z + a.w * b.w;
                }
                G[i][j] = s;
            }
            __syncthreads();
            if (tid < 16) {                  // wave-synchronous Cholesky + ridge
                float g[16], Lr[16];
#pragma unroll
                for (int j = 0; j < 16; j++) g[j] = G[tid][j];
                float tr = g[tid];
#pragma unroll
                for (int off = 8; off > 0; off >>= 1) tr += __shfl_xor(tr, off);
                g[tid] += (fin ? 1e-6f : 0.03f) * (tr * (1.0f / 16.0f));
#pragma unroll
                for (int j = 0; j < 16; j++) {
                    float s = g[j];
#pragma unroll
                    for (int k = 0; k < j; k++) s -= Lr[k] * __shfl(Lr[k], j);
                    float dj = __shfl(s, j);
                    float d = sqrtf(fmaxf(dj, 1e-20f));
                    Lr[j] = (tid == j) ? d : ((tid > j) ? s / d : 0.f);
                }
#pragma unroll
                for (int j = 0; j < 16; j++) Lc[tid][j] = Lr[j];
                rinvs[tid] = 1.0f / Lc[tid][tid];
            }
            __syncthreads();
            if (tid < 128) {                 // trisolve per column (mul by rinv)
                int m = tid;
                float q[16];
#pragma unroll
                for (int j = 0; j < 16; j++) {
                    float s = Yt[j][m];
#pragma unroll
                    for (int k = 0; k < j; k++) s -= Lc[j][k] * q[k];
                    q[j] = s * rinvs[j];
                }
                if (fin) {
                    float* ub = U + (size_t)mat * KSUB * PD;
#pragma unroll
                    for (int j = 0; j < 16; j++) ub[j * PD + m] = q[j];
                } else {
#pragma unroll
                    for (int j = 0; j < 16; j++) Qbf[cur ^ 1][j][m] = f2bf(q[j]);
                }
            }
            cur ^= 1;
        }
    }
}

// ------------------------------------------------------------------
// K4: pairwise ||U_a^T U_b||_F^2. grid 114, block 256.
// ------------------------------------------------------------------
__global__ __launch_bounds__(256) void k_gram(const float* __restrict__ U,
                                              float* __restrict__ cross,
                                              float* __restrict__ gram) {
    __shared__ float red[256];
    int bid = blockIdx.x;
    int ma, mb; bool isCross;
    if (bid < 66) {
        int a = 0, rem = bid;
        while (rem >= 11 - a) { rem -= 11 - a; a++; }
        ma = a; mb = a + 1 + rem; isCross = true;
    } else {
        int idx = bid - 66;
        ma = 12 + idx / 12; mb = idx % 12; isCross = false;
    }
    int tid = threadIdx.x;
    int i = tid >> 4, j = tid & 15;
    const float* ua = U + ((size_t)ma * KSUB + i) * PD;
    const float* ub = U + ((size_t)mb * KSUB + j) * PD;
    float s = 0.f;
    for (int m = 0; m < PD; m += 4) {
        float4 x = *(const float4*)(ua + m);
        float4 y = *(const float4*)(ub + m);
        s += x.x * y.x + x.y * y.y + x.z * y.z + x.w * y.w;
    }
    red[tid] = s * s;
    __syncthreads();
    for (int st = 128; st > 0; st >>= 1) {
        if (tid < st) red[tid] += red[tid + st];
        __syncthreads();
    }
    if (tid == 0) {
        if (isCross) { cross[ma * L_T + mb] = red[0]; cross[mb * L_T + ma] = red[0]; }
        else gram[(ma - 12) * L_T + mb] = red[0];
    }
}

// ------------------------------------------------------------------
// K5: softmax weights + reg_loss. 1 block, 128 threads.
// ------------------------------------------------------------------
__global__ __launch_bounds__(128) void k_weights(const float* __restrict__ gram,
                                                 const float* __restrict__ cross,
                                                 const float* __restrict__ mu,
                                                 const float* __restrict__ logt,
                                                 float* __restrict__ w,
                                                 float* __restrict__ loss_out) {
    __shared__ float wsm[P_S][L_T];
    __shared__ float red[128];
    int tid = threadIdx.x;
    if (tid < P_S) {
        float tau = log1pf(expf(logt[tid]));
        float x[L_T];
        float mx = -1e30f;
#pragma unroll
        for (int l = 0; l < L_T; l++) {
            float d = 1.0f - gram[tid * L_T + l] * (1.0f / 16.0f);
            x[l] = -d / tau;
            mx = fmaxf(mx, x[l]);
        }
        float ssum = 0.f;
#pragma unroll
        for (int l = 0; l < L_T; l++) { x[l] = expf(x[l] - mx); ssum += x[l]; }
        float inv = 1.0f / ssum;
#pragma unroll
        for (int l = 0; l < L_T; l++) { float wv = x[l] * inv; wsm[tid][l] = wv; w[tid * L_T + l] = wv; }
    }
    __syncthreads();
    float racc = 0.f;
    {
        int q = tid;
#pragma unroll
        for (int p = 0; p < P_S; p++) {
            float zm = 0.f;
#pragma unroll
            for (int l = 0; l < L_T; l++) zm += wsm[p][l] * mu[l * PD + q];
            float d = zm - mu[(12 + p) * PD + q];
            racc += d * d;
        }
    }
    red[tid] = racc;
    __syncthreads();
    for (int st = 64; st > 0; st >>= 1) {
        if (tid < st) red[tid] += red[tid + st];
        __syncthreads();
    }
    if (tid == 0) {
        float recon = red[0] * (1.0f / PD);
        float orth = 0.f;
        for (int p = 0; p < P_S; p++)
            for (int a = 0; a < L_T; a++)
                for (int b = 0; b < L_T; b++)
                    if (a != b) orth += wsm[p][a] * wsm[p][b] * cross[a * L_T + b];
        orth *= 0.5f;
        loss_out[0] = 0.01f * orth / P_S + 0.01f * recon / P_S;
    }
}

// ------------------------------------------------------------------
// K6: fused mix (teachers + attns), nontemporal streaming.
// ------------------------------------------------------------------
#define MIX_TB 1280
#define MIX_AB 3840
__global__ __launch_bounds__(256) void k_mix2(const float* __restrict__ Tt,
                                              const float* __restrict__ Ta,
                                              const float* __restrict__ w,
                                              float* __restrict__ outT,
                                              float* __restrict__ outA) {
    float wr[P_S][L_T];
#pragma unroll
    for (int p = 0; p < P_S; p++)
#pragma unroll
        for (int l = 0; l < L_T; l++) wr[p][l] = w[p * L_T + l];
    const float* in; float* out; size_t nl; int nv, v0, stride;
    if (blockIdx.x < MIX_TB) {
        in = Tt; out = outT; nl = (size_t)MROWS * DT;
        nv = (int)(nl / 4);
        v0 = blockIdx.x * 256 + threadIdx.x;
        stride = MIX_TB * 256;
    } else {
        in = Ta; out = outA; nl = (size_t)32 * 12 * 197 * 197;
        nv = (int)(nl / 4);
        v0 = (blockIdx.x - MIX_TB) * 256 + threadIdx.x;
        stride = MIX_AB * 256;
    }
    for (int v = v0; v < nv; v += stride) {
        f32x4 o[P_S];
#pragma unroll
        for (int p = 0; p < P_S; p++) o[p] = (f32x4){0.f, 0.f, 0.f, 0.f};
#pragma unroll
        for (int l = 0; l < L_T; l++) {
            f32x4 x = __builtin_nontemporal_load((const f32x4*)(in + (size_t)l * nl) + v);
#pragma unroll
            for (int p = 0; p < P_S; p++) {
                o[p][0] += wr[p][l] * x[0]; o[p][1] += wr[p][l] * x[1];
                o[p][2] += wr[p][l] * x[2]; o[p][3] += wr[p][l] * x[3];
            }
        }
#pragma unroll
        for (int p = 0; p < P_S; p++)
            __builtin_nontemporal_store(o[p], (f32x4*)(out + (size_t)p * nl) + v);
    }
}

extern "C" void kernel_launch(void* const* d_in, const int* in_sizes, int n_in,
                              void* d_out, int out_size, void* d_ws, size_t ws_size,
                              hipStream_t stream) {
    const float* student  = (const float*)d_in[0];
    const float* teacherT = (const float*)d_in[1];
    const float* teacherA = (const float*)d_in[2];
    const float* phis     = (const float*)d_in[3];
    const float* phit     = (const float*)d_in[4];
    const float* logt     = (const float*)d_in[5];
    float* out = (float*)d_out;

    char* ws = (char*)d_ws;
    float* spart = (float*)(ws + SPART_B);
    float* cs_g  = (float*)(ws + CS_B);
    float* mu    = (float*)(ws + MU_B);
    short* covb  = (short*)(ws + COVB_B);
    float* U     = (float*)(ws + U_B);
    float* cross = (float*)(ws + CROSS_B);
    float* gram  = (float*)(ws + GRAM_B);
    float* w     = (float*)(ws + W_B);
    short* wbt   = (short*)(ws + WBT_B);
    short* wbs   = (short*)(ws + WBS_B);

    k_init<<<152, 256, 0, stream>>>(phit, phis, wbt, wbs, cs_g);
    k_zcov<<<dim3(NBLK, 16), 256, 0, stream>>>(teacherT, student, wbt, wbs, spart, cs_g);
    k_covred<<<dim3(8, 16), 256, 0, stream>>>(spart, cs_g, mu, covb);
    k_eigen<<<16, 512, 0, stream>>>(covb, U);
    k_gram<<<114, 256, 0, stream>>>(U, cross, gram);
    k_weights<<<1, 128, 0, stream>>>(gram, cross, mu, logt, w, out + 78976512);
    k_mix2<<<MIX_TB + MIX_AB, 256, 0, stream>>>(teacherT, teacherA, w,
                                                out, out + 19365888);
}

// Round 8
// 381.003 us; speedup vs baseline: 6.8209x; 1.3497x over previous
//
#include <hip/hip_runtime.h>
#include <hip/hip_bf16.h>
#include <stdint.h>

typedef __attribute__((ext_vector_type(8))) short s16x8;
typedef __attribute__((ext_vector_type(4))) short s16x4;
typedef __attribute__((ext_vector_type(4))) float f32x4;

#define L_T 12
#define P_S 4
#define NMAT 16
#define MROWS 6304
#define PD 128
#define DT 768
#define DS 384
#define KSUB 16
#define NIT 12
#define NBLK 50

// ---- workspace byte offsets (16B aligned) ----
#define SPART_B 0            // 16*50*16384 f32 = 52,428,800
#define CS_B    52428800     // 2048 f32 (zeroed)
#define MU_B    52436992
#define COVB_B  52445184     // 16*16384 bf16
#define U_B     52969472
#define CROSS_B 53100544
#define GRAM_B  53101568
#define W_B     53102592
#define WBT_B   53103616
#define WBS_B   53300224

__device__ __forceinline__ short f2bf(float f) {
    __hip_bfloat16 h = __float2bfloat16(f);
    return *reinterpret_cast<short*>(&h);
}
__device__ __forceinline__ float bf2f(short s) {
    union { uint32_t u; float f; } c;
    c.u = ((uint32_t)(uint16_t)s) << 16;
    return c.f;
}

// ------------------------------------------------------------------
// K0: blocks [0,144): phi fp32->bf16; blocks [144,152): zero cs.
// ------------------------------------------------------------------
__global__ __launch_bounds__(256) void k_init(const float* __restrict__ phit,
                                              const float* __restrict__ phis,
                                              short* __restrict__ wbt,
                                              short* __restrict__ wbs,
                                              float* __restrict__ cs) {
    int b = blockIdx.x;
    if (b < 144) {
        int e = (b * 256 + threadIdx.x) * 4;
        const float* src; short* dst; int off;
        if (e < PD * DT) { src = phit; dst = wbt; off = e; }
        else             { src = phis; dst = wbs; off = e - PD * DT; }
        float4 v = *(const float4*)(src + off);
        s16x4 h;
        h[0] = f2bf(v.x); h[1] = f2bf(v.y); h[2] = f2bf(v.z); h[3] = f2bf(v.w);
        *(s16x4*)(dst + off) = h;
    } else {
        cs[(b - 144) * 256 + threadIdx.x] = 0.f;
    }
}

// ------------------------------------------------------------------
// K1: fused projection + covariance partials. grid (50,16), block 256.
// LDS overlay: Zs (34.8KB) aliases As+Ws (20.5KB) -> 34.8KB total,
// 4 blocks/CU. __launch_bounds__(256,4) caps VGPR at 128.
// ------------------------------------------------------------------
__global__ __launch_bounds__(256, 4) void k_zcov(const float* __restrict__ Tt,
                                                 const float* __restrict__ St,
                                                 const short* __restrict__ wbt,
                                                 const short* __restrict__ wbs,
                                                 float* __restrict__ spart,
                                                 float* __restrict__ cs_g) {
    __shared__ char smem[128 * 136 * 2];                 // 34816 B
    short (*As)[40] = (short(*)[40])smem;                // 10240 B
    short (*Ws)[40] = (short(*)[40])(smem + 10240);      // 10240 B
    short (*Zs)[136] = (short(*)[136])smem;              // aliases As+Ws
    int mat = blockIdx.y;
    const float* A; const short* Wb; int D;
    if (mat < L_T) { A = Tt + (size_t)mat * MROWS * DT; Wb = wbt; D = DT; }
    else           { A = St + (size_t)(mat - L_T) * MROWS * DS; Wb = wbs; D = DS; }
    int m0 = blockIdx.x * 128;
    int tid = threadIdx.x;
    int wid = tid >> 6, lane = tid & 63;
    int rw = lane & 15, kb = lane >> 4;
    f32x4 acc[2][8];
#pragma unroll
    for (int r = 0; r < 2; r++)
#pragma unroll
        for (int c = 0; c < 8; c++) acc[r][c] = (f32x4){0.f, 0.f, 0.f, 0.f};

    for (int d0 = 0; d0 < D; d0 += 32) {
        __syncthreads();
#pragma unroll
        for (int ii = 0; ii < 4; ii++) {
            int f = tid + 256 * ii;
            int row = f >> 3, c4 = (f & 7) << 2;
            int m = m0 + row;
            float4 v = make_float4(0.f, 0.f, 0.f, 0.f);
            if (m < MROWS) v = *(const float4*)(A + (size_t)m * D + d0 + c4);
            s16x4 h;
            h[0] = f2bf(v.x); h[1] = f2bf(v.y); h[2] = f2bf(v.z); h[3] = f2bf(v.w);
            *(s16x4*)&As[row][c4] = h;
        }
#pragma unroll
        for (int ii = 0; ii < 2; ii++) {
            int f = tid + 256 * ii;
            int row = f >> 2, c8 = (f & 3) << 3;
            *(s16x8*)&Ws[row][c8] = *(const s16x8*)(Wb + (size_t)row * D + d0 + c8);
        }
        __syncthreads();
        s16x8 ah[2];
#pragma unroll
        for (int r = 0; r < 2; r++)
            ah[r] = *(s16x8*)&As[32 * wid + 16 * r + rw][kb * 8];
#pragma unroll
        for (int c = 0; c < 8; c++) {
            s16x8 wv = *(s16x8*)&Ws[16 * c + rw][kb * 8];
#pragma unroll
            for (int r = 0; r < 2; r++)
                acc[r][c] = __builtin_amdgcn_mfma_f32_16x16x32_bf16(ah[r], wv, acc[r][c], 0, 0, 0);
        }
    }
    __syncthreads();   // GEMM phase done; safe to overwrite As/Ws with Zs
#pragma unroll
    for (int c = 0; c < 8; c++) {
        int q = 16 * c + rw;
#pragma unroll
        for (int r = 0; r < 2; r++) {
            s16x4 o;
            o[0] = f2bf(acc[r][c][0]); o[1] = f2bf(acc[r][c][1]);
            o[2] = f2bf(acc[r][c][2]); o[3] = f2bf(acc[r][c][3]);
            *(s16x4*)&Zs[q][32 * wid + 16 * r + 4 * kb] = o;
        }
    }
    __syncthreads();
    if (tid < 128) {
        float s = 0.f;
#pragma unroll
        for (int mm = 0; mm < 128; mm += 8) {
            s16x8 v = *(s16x8*)&Zs[tid][mm];
#pragma unroll
            for (int u = 0; u < 8; u++) s += bf2f(v[u]);
        }
        atomicAdd(cs_g + mat * PD + tid, s);
    }
    f32x4 a2[2][8];
#pragma unroll
    for (int r = 0; r < 2; r++)
#pragma unroll
        for (int cc = 0; cc < 8; cc++) a2[r][cc] = (f32x4){0.f, 0.f, 0.f, 0.f};
#pragma unroll
    for (int kc = 0; kc < 4; kc++) {
        s16x8 fr[8];
#pragma unroll
        for (int t = 0; t < 8; t++) fr[t] = *(s16x8*)&Zs[16 * t + rw][kc * 32 + kb * 8];
#pragma unroll
        for (int r = 0; r < 2; r++)
#pragma unroll
            for (int cc = 0; cc < 8; cc++)
                a2[r][cc] = __builtin_amdgcn_mfma_f32_16x16x32_bf16(
                    fr[2 * wid + r], fr[cc], a2[r][cc], 0, 0, 0);
    }
    float* sb = spart + ((size_t)mat * NBLK + blockIdx.x) * 16384;
#pragma unroll
    for (int r = 0; r < 2; r++)
#pragma unroll
        for (int cc = 0; cc < 8; cc++)
#pragma unroll
            for (int rr = 0; rr < 4; rr++) {
                int row = (2 * wid + r) * 16 + 4 * kb + rr;
                int col = 16 * cc + rw;
                sb[row * 128 + col] = a2[r][cc][rr];
            }
}

// ------------------------------------------------------------------
// K2: reduce S-partials, finalize cov -> bf16, write mu. grid (8,16).
// ------------------------------------------------------------------
__global__ __launch_bounds__(256) void k_covred(const float* __restrict__ spart,
                                                const float* __restrict__ cs_g,
                                                float* __restrict__ mu_g,
                                                short* __restrict__ covb) {
    int mat = blockIdx.y, seg = blockIdx.x;
    int tid = threadIdx.x;
    int e0 = (seg * 256 + tid) * 8;
    float s[8];
#pragma unroll
    for (int u = 0; u < 8; u++) s[u] = 0.f;
    const float* base = spart + (size_t)mat * NBLK * 16384 + e0;
    for (int b = 0; b < NBLK; b++) {
        const float* p = base + (size_t)b * 16384;
        float4 u0 = *(const float4*)(p);
        float4 u1 = *(const float4*)(p + 4);
        s[0] += u0.x; s[1] += u0.y; s[2] += u0.z; s[3] += u0.w;
        s[4] += u1.x; s[5] += u1.y; s[6] += u1.z; s[7] += u1.w;
    }
    int i = e0 >> 7, j0 = e0 & 127;
    float mi = cs_g[mat * PD + i] * (1.0f / MROWS);
    s16x8 o;
#pragma unroll
    for (int u = 0; u < 8; u++) {
        float mj = cs_g[mat * PD + j0 + u] * (1.0f / MROWS);
        o[u] = f2bf(s[u] * (1.0f / MROWS) - mi * mj);
    }
    *(s16x8*)(covb + (size_t)mat * 16384 + e0) = o;
    if (seg == 0 && tid < 128)
        mu_g[mat * PD + tid] = cs_g[mat * PD + tid] * (1.0f / MROWS);
}

// ------------------------------------------------------------------
// K3: top-16 invariant subspace. grid 16, block 512. NIT=12,
// CholQR at it 3,7,11 (final fp32).
// ------------------------------------------------------------------
__global__ __launch_bounds__(512) void k_eigen(const short* __restrict__ covb,
                                               float* __restrict__ U) {
    __shared__ short Abf[128][136];
    __shared__ short Qbf[2][16][136];
    __shared__ float Yt[16][132];
    __shared__ float G[16][17];
    __shared__ float Lc[16][17];
    __shared__ float rinvs[16];
    int mat = blockIdx.x, tid = threadIdx.x;
    int wid = tid >> 6, lane = tid & 63;
    int rw = lane & 15, kb = lane >> 4;
    {
        int row = tid >> 2, sg = (tid & 3) << 5;
        const short* src = covb + (size_t)mat * 16384 + row * 128 + sg;
#pragma unroll
        for (int k = 0; k < 4; k++)
            *(s16x8*)&Abf[row][sg + 8 * k] = *(const s16x8*)(src + 8 * k);
    }
    {
#pragma unroll
        for (int u = 0; u < 4; u++) {
            int e = tid * 4 + u;
            int j = e >> 7, m = e & 127;
            uint32_t x = (uint32_t)e ^ (0x9E3779B9u * (uint32_t)(mat + 1));
            x ^= x >> 16; x *= 0x7feb352du; x ^= x >> 15; x *= 0x846ca68bu; x ^= x >> 16;
            float v = (float)(int)x * 4.6566129e-10f;
            Qbf[0][j][m] = f2bf(v);
        }
    }
    __syncthreads();
    s16x8 areg[4];
#pragma unroll
    for (int kc = 0; kc < 4; kc++)
        areg[kc] = *(s16x8*)&Abf[16 * wid + rw][kc * 32 + kb * 8];

    int cur = 0;
    for (int it = 0; it < NIT; it++) {
        __syncthreads();
        f32x4 acc = (f32x4){0.f, 0.f, 0.f, 0.f};
#pragma unroll
        for (int kc = 0; kc < 4; kc++) {
            s16x8 b = *(s16x8*)&Qbf[cur][rw][kc * 32 + kb * 8];
            acc = __builtin_amdgcn_mfma_f32_16x16x32_bf16(areg[kc], b, acc, 0, 0, 0);
        }
        bool fin = (it == NIT - 1);
        bool orth = ((it & 3) == 3) || fin;
        if (!orth) {
            s16x4 sv;
            sv[0] = f2bf(acc[0]); sv[1] = f2bf(acc[1]);
            sv[2] = f2bf(acc[2]); sv[3] = f2bf(acc[3]);
            *(s16x4*)&Qbf[cur ^ 1][rw][16 * wid + 4 * kb] = sv;
            cur ^= 1;
        } else {
            *(f32x4*)&Yt[rw][16 * wid + 4 * kb] = acc;
            __syncthreads();
            if (tid < 256) {
                int i = tid >> 4, j = tid & 15;
                float s = 0.f;
                for (int mm = 0; mm < 128; mm += 4) {
                    float4 a = *(float4*)&Yt[i][mm];
                    float4 b = *(float4*)&Yt[j][mm];
                    s += a.x * b.x + a.y * b.y + a.z * b.z + a.w * b.w;
                }
                G[i][j] = s;
            }
            __syncthreads();
            if (tid < 16) {
                float g[16], Lr[16];
#pragma unroll
                for (int j = 0; j < 16; j++) g[j] = G[tid][j];
                float tr = g[tid];
#pragma unroll
                for (int off = 8; off > 0; off >>= 1) tr += __shfl_xor(tr, off);
                g[tid] += (fin ? 1e-6f : 0.03f) * (tr * (1.0f / 16.0f));
#pragma unroll
                for (int j = 0; j < 16; j++) {
                    float s = g[j];
#pragma unroll
                    for (int k = 0; k < j; k++) s -= Lr[k] * __shfl(Lr[k], j);
                    float dj = __shfl(s, j);
                    float d = sqrtf(fmaxf(dj, 1e-20f));
                    Lr[j] = (tid == j) ? d : ((tid > j) ? s / d : 0.f);
                }
#pragma unroll
                for (int j = 0; j < 16; j++) Lc[tid][j] = Lr[j];
                rinvs[tid] = 1.0f / Lc[tid][tid];
            }
            __syncthreads();
            if (tid < 128) {
                int m = tid;
                float q[16];
#pragma unroll
                for (int j = 0; j < 16; j++) {
                    float s = Yt[j][m];
#pragma unroll
                    for (int k = 0; k < j; k++) s -= Lc[j][k] * q[k];
                    q[j] = s * rinvs[j];
                }
                if (fin) {
                    float* ub = U + (size_t)mat * KSUB * PD;
#pragma unroll
                    for (int j = 0; j < 16; j++) ub[j * PD + m] = q[j];
                } else {
#pragma unroll
                    for (int j = 0; j < 16; j++) Qbf[cur ^ 1][j][m] = f2bf(q[j]);
                }
            }
            cur ^= 1;
        }
    }
}

// ------------------------------------------------------------------
// K4: pairwise ||U_a^T U_b||_F^2. grid 114, block 256.
// ------------------------------------------------------------------
__global__ __launch_bounds__(256) void k_gram(const float* __restrict__ U,
                                              float* __restrict__ cross,
                                              float* __restrict__ gram) {
    __shared__ float red[256];
    int bid = blockIdx.x;
    int ma, mb; bool isCross;
    if (bid < 66) {
        int a = 0, rem = bid;
        while (rem >= 11 - a) { rem -= 11 - a; a++; }
        ma = a; mb = a + 1 + rem; isCross = true;
    } else {
        int idx = bid - 66;
        ma = 12 + idx / 12; mb = idx % 12; isCross = false;
    }
    int tid = threadIdx.x;
    int i = tid >> 4, j = tid & 15;
    const float* ua = U + ((size_t)ma * KSUB + i) * PD;
    const float* ub = U + ((size_t)mb * KSUB + j) * PD;
    float s = 0.f;
    for (int m = 0; m < PD; m += 4) {
        float4 x = *(const float4*)(ua + m);
        float4 y = *(const float4*)(ub + m);
        s += x.x * y.x + x.y * y.y + x.z * y.z + x.w * y.w;
    }
    red[tid] = s * s;
    __syncthreads();
    for (int st = 128; st > 0; st >>= 1) {
        if (tid < st) red[tid] += red[tid + st];
        __syncthreads();
    }
    if (tid == 0) {
        if (isCross) { cross[ma * L_T + mb] = red[0]; cross[mb * L_T + ma] = red[0]; }
        else gram[(ma - 12) * L_T + mb] = red[0];
    }
}

// ------------------------------------------------------------------
// K5: softmax weights + reg_loss. 1 block, 128 threads.
// ------------------------------------------------------------------
__global__ __launch_bounds__(128) void k_weights(const float* __restrict__ gram,
                                                 const float* __restrict__ cross,
                                                 const float* __restrict__ mu,
                                                 const float* __restrict__ logt,
                                                 float* __restrict__ w,
                                                 float* __restrict__ loss_out) {
    __shared__ float wsm[P_S][L_T];
    __shared__ float red[128];
    int tid = threadIdx.x;
    if (tid < P_S) {
        float tau = log1pf(expf(logt[tid]));
        float x[L_T];
        float mx = -1e30f;
#pragma unroll
        for (int l = 0; l < L_T; l++) {
            float d = 1.0f - gram[tid * L_T + l] * (1.0f / 16.0f);
            x[l] = -d / tau;
            mx = fmaxf(mx, x[l]);
        }
        float ssum = 0.f;
#pragma unroll
        for (int l = 0; l < L_T; l++) { x[l] = expf(x[l] - mx); ssum += x[l]; }
        float inv = 1.0f / ssum;
#pragma unroll
        for (int l = 0; l < L_T; l++) { float wv = x[l] * inv; wsm[tid][l] = wv; w[tid * L_T + l] = wv; }
    }
    __syncthreads();
    float racc = 0.f;
    {
        int q = tid;
#pragma unroll
        for (int p = 0; p < P_S; p++) {
            float zm = 0.f;
#pragma unroll
            for (int l = 0; l < L_T; l++) zm += wsm[p][l] * mu[l * PD + q];
            float d = zm - mu[(12 + p) * PD + q];
            racc += d * d;
        }
    }
    red[tid] = racc;
    __syncthreads();
    for (int st = 64; st > 0; st >>= 1) {
        if (tid < st) red[tid] += red[tid + st];
        __syncthreads();
    }
    if (tid == 0) {
        float recon = red[0] * (1.0f / PD);
        float orth = 0.f;
        for (int p = 0; p < P_S; p++)
            for (int a = 0; a < L_T; a++)
                for (int b = 0; b < L_T; b++)
                    if (a != b) orth += wsm[p][a] * wsm[p][b] * cross[a * L_T + b];
        orth *= 0.5f;
        loss_out[0] = 0.01f * orth / P_S + 0.01f * recon / P_S;
    }
}

// ------------------------------------------------------------------
// K6: fused mix (teachers + attns), nontemporal streaming.
// ------------------------------------------------------------------
#define MIX_TB 1280
#define MIX_AB 3840
__global__ __launch_bounds__(256) void k_mix2(const float* __restrict__ Tt,
                                              const float* __restrict__ Ta,
                                              const float* __restrict__ w,
                                              float* __restrict__ outT,
                                              float* __restrict__ outA) {
    float wr[P_S][L_T];
#pragma unroll
    for (int p = 0; p < P_S; p++)
#pragma unroll
        for (int l = 0; l < L_T; l++) wr[p][l] = w[p * L_T + l];
    const float* in; float* out; size_t nl; int nv, v0, stride;
    if (blockIdx.x < MIX_TB) {
        in = Tt; out = outT; nl = (size_t)MROWS * DT;
        nv = (int)(nl / 4);
        v0 = blockIdx.x * 256 + threadIdx.x;
        stride = MIX_TB * 256;
    } else {
        in = Ta; out = outA; nl = (size_t)32 * 12 * 197 * 197;
        nv = (int)(nl / 4);
        v0 = (blockIdx.x - MIX_TB) * 256 + threadIdx.x;
        stride = MIX_AB * 256;
    }
    for (int v = v0; v < nv; v += stride) {
        f32x4 o[P_S];
#pragma unroll
        for (int p = 0; p < P_S; p++) o[p] = (f32x4){0.f, 0.f, 0.f, 0.f};
#pragma unroll
        for (int l = 0; l < L_T; l++) {
            f32x4 x = __builtin_nontemporal_load((const f32x4*)(in + (size_t)l * nl) + v);
#pragma unroll
            for (int p = 0; p < P_S; p++) {
                o[p][0] += wr[p][l] * x[0]; o[p][1] += wr[p][l] * x[1];
                o[p][2] += wr[p][l] * x[2]; o[p][3] += wr[p][l] * x[3];
            }
        }
#pragma unroll
        for (int p = 0; p < P_S; p++)
            __builtin_nontemporal_store(o[p], (f32x4*)(out + (size_t)p * nl) + v);
    }
}

extern "C" void kernel_launch(void* const* d_in, const int* in_sizes, int n_in,
                              void* d_out, int out_size, void* d_ws, size_t ws_size,
                              hipStream_t stream) {
    const float* student  = (const float*)d_in[0];
    const float* teacherT = (const float*)d_in[1];
    const float* teacherA = (const float*)d_in[2];
    const float* phis     = (const float*)d_in[3];
    const float* phit     = (const float*)d_in[4];
    const float* logt     = (const float*)d_in[5];
    float* out = (float*)d_out;

    char* ws = (char*)d_ws;
    float* spart = (float*)(ws + SPART_B);
    float* cs_g  = (float*)(ws + CS_B);
    float* mu    = (float*)(ws + MU_B);
    short* covb  = (short*)(ws + COVB_B);
    float* U     = (float*)(ws + U_B);
    float* cross = (float*)(ws + CROSS_B);
    float* gram  = (float*)(ws + GRAM_B);
    float* w     = (float*)(ws + W_B);
    short* wbt   = (short*)(ws + WBT_B);
    short* wbs   = (short*)(ws + WBS_B);

    k_init<<<152, 256, 0, stream>>>(phit, phis, wbt, wbs, cs_g);
    k_zcov<<<dim3(NBLK, 16), 256, 0, stream>>>(teacherT, student, wbt, wbs, spart, cs_g);
    k_covred<<<dim3(8, 16), 256, 0, stream>>>(spart, cs_g, mu, covb);
    k_eigen<<<16, 512, 0, stream>>>(covb, U);
    k_gram<<<114, 256, 0, stream>>>(U, cross, gram);
    k_weights<<<1, 128, 0, stream>>>(gram, cross, mu, logt, w, out + 78976512);
    k_mix2<<<MIX_TB + MIX_AB, 256, 0, stream>>>(teacherT, teacherA, w,
                                                out, out + 19365888);
}